// Round 1
// baseline (5669.540 us; speedup 1.0000x reference)
//
#include <hip/hip_runtime.h>
#include <hip/hip_bf16.h>

// Problem constants (fixed by the reference)
#define NPG    128       // nodes per graph
#define EPG    1024      // edges per graph
#define BG     512       // graphs
#define STRIDE 65        // LDS row stride (64 + 1 pad -> bank spread)
#define PHI    0.1f
#define EPSV   1e-5f

// d_out float offsets: output[512] | g_out[512*192] | aug_g_out[512*192] | loss[1]
#define OUT_G    512
#define OUT_AUG  98816
#define OUT_LOSS 197120

// workspace float offsets
#define WS_EMB  0          // emb_rel [16*64]
#define WS_RELE 1024       // rel_e   [16*64]
#define WS_REPG 2048       // rep_g   [65536*192]

// ---------------------------------------------------------------------------
// Prologue: emb_rel = relu(rel_feat @ rel_proj_W + b); rel_e = relu(emb_rel @ dec_Wr + br)
// Also zeroes the loss accumulator slot.
// ---------------------------------------------------------------------------
__global__ __launch_bounds__(256) void k_prologue(
    const float* __restrict__ rel_feat, const float* __restrict__ rpW,
    const float* __restrict__ rpb, const float* __restrict__ dWr,
    const float* __restrict__ dbr, float* __restrict__ ws, float* __restrict__ out) {
  __shared__ float emb[16 * 64];
  int tid = threadIdx.x;
  for (int idx = tid; idx < 1024; idx += 256) {
    int r = idx >> 6, j = idx & 63;
    float s = rpb[j];
    for (int k = 0; k < 64; k++) s = fmaf(rel_feat[r * 64 + k], rpW[k * 64 + j], s);
    s = fmaxf(s, 0.f);
    emb[idx] = s;
    ws[WS_EMB + idx] = s;
  }
  __syncthreads();
  for (int idx = tid; idx < 1024; idx += 256) {
    int r = idx >> 6, j = idx & 63;
    float s = dbr[j];
    for (int k = 0; k < 64; k++) s = fmaf(emb[r * 64 + k], dWr[k * 64 + j], s);
    ws[WS_RELE + idx] = fmaxf(s, 0.f);
  }
  if (tid == 0) out[OUT_LOSS] = 0.f;
}

// ---------------------------------------------------------------------------
// Build per-graph edge list bucketed by etype, each bucket padded to 64 slots
// so every 64-lane wave chunk is relation-uniform (enables SGPR weight loads).
// entry: src(7b)<<12 | dst(7b)<<5 | et(4b)<<1 | w(1b). Padding slots are 0 (w=0).
// ---------------------------------------------------------------------------
__device__ void build_elist(unsigned* elist, int* counts, int* offs, int* pnc,
                            const unsigned* maskbits, int useMask,
                            const int* __restrict__ et_a, const int* __restrict__ src_a,
                            const int* __restrict__ dst_a, int ge, int gn, int tid) {
  if (tid < 16) counts[tid] = 0;
  __syncthreads();
  for (int i = tid; i < EPG; i += 256) {
    int keep = useMask ? (int)((maskbits[i >> 5] >> (i & 31)) & 1u) : 1;
    if (keep) atomicAdd(&counts[et_a[ge + i]], 1);
  }
  __syncthreads();
  if (tid == 0) {
    int o = 0;
    for (int r = 0; r < 16; r++) { offs[r] = o; o += ((counts[r] + 63) >> 6) << 6; }
    offs[16] = o;
    *pnc = o >> 6;
  }
  __syncthreads();
  int total = offs[16];
  for (int s = tid; s < total; s += 256) elist[s] = 0u;
  __syncthreads();
  if (tid < 16) counts[tid] = offs[tid];  // reuse as cursors
  __syncthreads();
  for (int i = tid; i < EPG; i += 256) {
    int keep = useMask ? (int)((maskbits[i >> 5] >> (i & 31)) & 1u) : 1;
    if (keep) {
      int r = et_a[ge + i];
      int pos = atomicAdd(&counts[r], 1);
      unsigned sl = (unsigned)(src_a[ge + i] - gn);
      unsigned dl = (unsigned)(dst_a[ge + i] - gn);
      elist[pos] = (sl << 12) | (dl << 5) | ((unsigned)r << 1) | 1u;
    }
  }
  __syncthreads();
}

// ---------------------------------------------------------------------------
// One RGCN layer: hout = relu(hin @ Wself + agg/max(deg,1) + b)
// Edge pass: lane = one edge; Wrel[r] rows read wave-uniformly (readfirstlane r).
// ---------------------------------------------------------------------------
__device__ void rgcn_layer(const float* hin, float* hout, float* deg,
                           const unsigned* elist, int nC,
                           const float* __restrict__ Wl, const float* __restrict__ Wsl,
                           const float* __restrict__ bl, int tid) {
  for (int i = tid; i < NPG * STRIDE; i += 256) hout[i] = 0.f;
  if (tid < NPG) deg[tid] = 0.f;
  __syncthreads();
  int lane = tid & 63, wave = tid >> 6;
  for (int c = wave; c < nC; c += 4) {
    unsigned e = elist[c * 64 + lane];
    int r_u = (__builtin_amdgcn_readfirstlane((int)e) >> 1) & 15;  // chunk-uniform etype
    const float* W = Wl + r_u * 4096;
    int srcv = (int)(e >> 12) & 127;
    int dstv = (int)(e >> 5) & 127;
    int w = (int)(e & 1u);
    float acc[64];
#pragma unroll
    for (int j = 0; j < 64; j++) acc[j] = 0.f;
    for (int k = 0; k < 64; k++) {
      float hk = hin[srcv * STRIDE + k];       // LDS, ~2-4-way conflicts (random rows)
      const float* wr = W + k * 64;            // wave-uniform -> s_load, SGPR-operand FMA
#pragma unroll
      for (int j = 0; j < 64; j++) acc[j] = fmaf(hk, wr[j], acc[j]);
    }
    if (w) {
#pragma unroll
      for (int j = 0; j < 64; j++) atomicAdd(&hout[dstv * STRIDE + j], acc[j]);
      atomicAdd(&deg[dstv], 1.0f);
    }
  }
  __syncthreads();
  // finalize: waves 0/1 -> j0=0, waves 2/3 -> j0=32; lane -> node row
  int v = ((wave & 1) << 6) | lane;
  int j0 = __builtin_amdgcn_readfirstlane((wave >> 1) << 5);
  float acc2[32];
#pragma unroll
  for (int j = 0; j < 32; j++) acc2[j] = 0.f;
  for (int k = 0; k < 64; k++) {
    float hk = hin[v * STRIDE + k];
    const float* wr = Wsl + k * 64 + j0;
#pragma unroll
    for (int j = 0; j < 32; j++) acc2[j] = fmaf(hk, wr[j], acc2[j]);
  }
  float inv = 1.0f / fmaxf(deg[v], 1.0f);
#pragma unroll
  for (int j = 0; j < 32; j++) {
    float val = acc2[j] + hout[v * STRIDE + j0 + j] * inv + bl[j0 + j];
    hout[v * STRIDE + j0 + j] = fmaxf(val, 0.f);
  }
  __syncthreads();
}

// ---------------------------------------------------------------------------
// Dense 64x64 per-node matmul over the 128-node LDS tile.
// mode 0: out = acc ; mode 1: out = relu(acc + bias) ; mode 2: out += sqrt(exp(acc))*eps
// preBarrier: barrier between reads and writes (for in-place out==in).
// ---------------------------------------------------------------------------
__device__ void dense64(const float* in, float* out, const float* __restrict__ W,
                        const float* __restrict__ bias, int mode,
                        const float* __restrict__ epsbuf, int gn, int tid, int preBarrier) {
  int lane = tid & 63, wave = tid >> 6;
  int v = ((wave & 1) << 6) | lane;
  int j0 = __builtin_amdgcn_readfirstlane((wave >> 1) << 5);
  float acc[32];
#pragma unroll
  for (int j = 0; j < 32; j++) acc[j] = 0.f;
  for (int k = 0; k < 64; k++) {
    float hk = in[v * STRIDE + k];
    const float* wr = W + k * 64 + j0;
#pragma unroll
    for (int j = 0; j < 32; j++) acc[j] = fmaf(hk, wr[j], acc[j]);
  }
  if (preBarrier) __syncthreads();
#pragma unroll
  for (int j = 0; j < 32; j++) {
    float a = acc[j];
    if (mode == 1) a = fmaxf(a + bias[j0 + j], 0.f);
    else if (mode == 2) a = out[v * STRIDE + j0 + j] + sqrtf(expf(a)) * epsbuf[(gn + v) * 64 + j0 + j];
    out[v * STRIDE + j0 + j] = a;
  }
  __syncthreads();
}

// ---------------------------------------------------------------------------
// Mega kernel: one workgroup per graph does the entire forward for that graph.
// ---------------------------------------------------------------------------
__global__ __launch_bounds__(256) void k_mega(
    const float* __restrict__ feat, const float* __restrict__ Wrel,
    const float* __restrict__ Wself, const float* __restrict__ bvec,
    const float* __restrict__ encWm, const float* __restrict__ encWs,
    const float* __restrict__ decWh, const float* __restrict__ dbh,
    const float* __restrict__ decWt, const float* __restrict__ dbt,
    const float* __restrict__ fcW, const float* __restrict__ fcb,
    const float* __restrict__ epsbuf,
    const int* __restrict__ srcA, const int* __restrict__ dstA, const int* __restrict__ etA,
    const int* __restrict__ asrcA, const int* __restrict__ adstA, const int* __restrict__ aetA,
    const int* __restrict__ rel_labels, float* __restrict__ ws, float* __restrict__ out) {
  __shared__ float buf0[NPG * STRIDE];
  __shared__ float buf1[NPG * STRIDE];
  __shared__ unsigned elist[2048];
  __shared__ float deg[NPG];
  __shared__ float red[128];
  __shared__ float ht[3 * 2 * 64];
  __shared__ float rgout[3 * 64];
  __shared__ unsigned maskbits[EPG / 32];
  __shared__ int counts[16];
  __shared__ int offs[17];
  __shared__ int nChunksSh;

  int g = blockIdx.x, tid = threadIdx.x;
  int gn = g * NPG, ge = g * EPG;
  float* repg = ws + WS_REPG;

  // ================= ORIG encode =================
  build_elist(elist, counts, offs, &nChunksSh, maskbits, 0, etA, srcA, dstA, ge, gn, tid);
  for (int i = tid; i < NPG * 64; i += 256)
    buf0[(i >> 6) * STRIDE + (i & 63)] = feat[(gn + (i >> 6)) * 64 + (i & 63)];
  __syncthreads();
  int nC = nChunksSh;
  for (int l = 0; l < 3; l++) {
    const float* hin = (l & 1) ? buf1 : buf0;
    float* hout = (l & 1) ? buf0 : buf1;
    rgcn_layer(hin, hout, deg, elist, nC, Wrel + l * 16 * 4096, Wself + l * 4096,
               bvec + l * 64, tid);
    for (int i = tid; i < NPG * 64; i += 256) {
      int v = i >> 6, j = i & 63;
      repg[(gn + v) * 192 + l * 64 + j] = hout[v * STRIDE + j];
    }
    if (tid < 64) {
      float s = 0.f;
      for (int v = 0; v < NPG; v++) s += hout[v * STRIDE + tid];
      out[OUT_G + g * 192 + l * 64 + tid] = s * (1.0f / 128.0f);
    }
    __syncthreads();
  }
  // ================= AUG encode =================
  build_elist(elist, counts, offs, &nChunksSh, maskbits, 0, aetA, asrcA, adstA, ge, gn, tid);
  for (int i = tid; i < NPG * 64; i += 256)
    buf0[(i >> 6) * STRIDE + (i & 63)] = feat[(gn + (i >> 6)) * 64 + (i & 63)];
  __syncthreads();
  nC = nChunksSh;
  for (int l = 0; l < 3; l++) {
    const float* hin = (l & 1) ? buf1 : buf0;
    float* hout = (l & 1) ? buf0 : buf1;
    rgcn_layer(hin, hout, deg, elist, nC, Wrel + l * 16 * 4096, Wself + l * 4096,
               bvec + l * 64, tid);
    if (tid < 64) {
      float s = 0.f;
      for (int v = 0; v < NPG; v++) s += hout[v * STRIDE + tid];
      out[OUT_AUG + g * 192 + l * 64 + tid] = s * (1.0f / 128.0f);
    }
    __syncthreads();
  }
  // aug_x now in buf1. Reload x (= rep_g layer 2) into buf0.
  for (int i = tid; i < NPG * 64; i += 256) {
    int v = i >> 6, j = i & 63;
    buf0[v * STRIDE + j] = repg[(gn + v) * 192 + 128 + j];
  }
  __syncthreads();
  // ================= AdaIN (style into buf0) =================
  if (tid < NPG) {
    int v = tid;
    float s1 = 0.f, s2 = 0.f;
    for (int j = 0; j < 64; j++) { float x = buf0[v * STRIDE + j]; s1 += x; s2 += x * x; }
    float mc = s1 * (1.f / 64.f);
    float sc = sqrtf((s2 - 64.f * mc * mc) * (1.f / 63.f) + EPSV);
    s1 = 0.f; s2 = 0.f;
    for (int j = 0; j < 64; j++) { float x = buf1[v * STRIDE + j]; s1 += x; s2 += x * x; }
    float ms = s1 * (1.f / 64.f);
    float ss = sqrtf((s2 - 64.f * ms * ms) * (1.f / 63.f) + EPSV);
    float sca = ss / sc;
    for (int j = 0; j < 64; j++) {
      float x = buf0[v * STRIDE + j];
      buf0[v * STRIDE + j] = (x - mc) * sca + ms;
    }
  }
  __syncthreads();
  // ================= VAE + decoder node transforms =================
  dense64(buf0, buf1, encWm, nullptr, 0, nullptr, gn, tid, 0);        // buf1 = z_mean
  dense64(buf0, buf1, encWs, nullptr, 2, epsbuf, gn, tid, 0);         // buf1 = z
  dense64(buf1, buf0, decWh, dbh, 1, nullptr, gn, tid, 0);            // buf0 = zh
  dense64(buf1, buf1, decWt, dbt, 1, nullptr, gn, tid, 1);            // buf1 = zt (in-place)
  // ================= edge logits -> mask bits =================
  for (int i = tid; i < EPG / 32; i += 256) maskbits[i] = 0u;
  __syncthreads();
  const float* rele = ws + WS_RELE;
  for (int i = tid; i < EPG; i += 256) {
    int s = srcA[ge + i] - gn, t = dstA[ge + i] - gn, r = etA[ge + i];
    const float* re = rele + r * 64;
    float lg = 0.f;
    for (int j = 0; j < 64; j++)
      lg = fmaf(buf0[s * STRIDE + j] * buf1[t * STRIDE + j], re[j], lg);
    if (lg >= 0.5f) atomicOr(&maskbits[i >> 5], 1u << (i & 31));
  }
  __syncthreads();
  if (tid == 0) maskbits[0] |= 1u;  // root edge forced kept
  __syncthreads();
  // ================= RECON encode (masked edges skipped entirely) =================
  build_elist(elist, counts, offs, &nChunksSh, maskbits, 1, etA, srcA, dstA, ge, gn, tid);
  for (int i = tid; i < NPG * 64; i += 256)
    buf0[(i >> 6) * STRIDE + (i & 63)] = feat[(gn + (i >> 6)) * 64 + (i & 63)];
  __syncthreads();
  nC = nChunksSh;
  const float c1 = 1.0f / (65536.0f * 64.0f);  // mse: mean over N and D
  const float c2 = PHI / 65536.0f;             // style: PHI * mean over N
  for (int l = 0; l < 3; l++) {
    const float* hin = (l & 1) ? buf1 : buf0;
    float* hout = (l & 1) ? buf0 : buf1;
    rgcn_layer(hin, hout, deg, elist, nC, Wrel + l * 16 * 4096, Wself + l * 4096,
               bvec + l * 64, tid);
    if (tid < 64) {
      float s = 0.f;
      for (int v = 0; v < NPG; v++) s += hout[v * STRIDE + tid];
      rgout[l * 64 + tid] = s * (1.0f / 128.0f);
    }
    if (tid >= 64 && tid < 192) {
      int i2 = tid - 64;               // rows 0 (head) and 1 (tail)
      int vv = i2 >> 6, j = i2 & 63;
      ht[(l * 2 + vv) * 64 + j] = hout[vv * STRIDE + j];
    }
    if (tid < NPG) {
      int v = tid;
      const float* grow = repg + (gn + v) * 192 + l * 64;
      float mse = 0.f, a1 = 0.f, a2 = 0.f, b1 = 0.f, b2 = 0.f;
      for (int j = 0; j < 64; j++) {
        float rc = hout[v * STRIDE + j];
        float gg = grow[j];
        float d = rc - gg;
        mse += d * d; a1 += rc; a2 += rc * rc; b1 += gg; b2 += gg * gg;
      }
      float mr = a1 * (1.f / 64.f), mg = b1 * (1.f / 64.f);
      float sr = sqrtf((a2 - 64.f * mr * mr) * (1.f / 63.f) + EPSV);
      float sg = sqrtf((b2 - 64.f * mg * mg) * (1.f / 63.f) + EPSV);
      float style = (mr - mg) * (mr - mg) + (sr - sg) * (sr - sg);
      red[v] = mse * c1 + style * c2;
    }
    __syncthreads();
    for (int s = 64; s > 0; s >>= 1) {
      if (tid < s) red[tid] += red[tid + s];
      __syncthreads();
    }
    if (tid == 0) atomicAdd(&out[OUT_LOSS], red[0]);
    __syncthreads();
  }
  // ================= final fc output =================
  if (tid < 64) {
    int rl = rel_labels[g];
    const float* emb = ws + WS_EMB + rl * 64;
    float s = 0.f;
    for (int p = 0; p < 10; p++) {
      int i = p * 64 + tid;
      float gr;
      if (i < 192) gr = rgout[i];
      else if (i < 384) { int i2 = i - 192; gr = ht[((i2 >> 6) * 2 + 0) * 64 + (i2 & 63)]; }
      else if (i < 576) { int i2 = i - 384; gr = ht[((i2 >> 6) * 2 + 1) * 64 + (i2 & 63)]; }
      else gr = emb[i - 576];
      s = fmaf(gr, fcW[i], s);
    }
#pragma unroll
    for (int o = 32; o > 0; o >>= 1) s += __shfl_down(s, o);
    if (tid == 0) out[g] = s + fcb[0];
  }
}

extern "C" void kernel_launch(void* const* d_in, const int* in_sizes, int n_in,
                              void* d_out, int out_size, void* d_ws, size_t ws_size,
                              hipStream_t stream) {
  const float* feat     = (const float*)d_in[0];
  const float* rel_feat = (const float*)d_in[1];
  const float* rpW      = (const float*)d_in[2];
  const float* rpb      = (const float*)d_in[3];
  const float* Wrel     = (const float*)d_in[4];
  const float* Wself    = (const float*)d_in[5];
  const float* bvec     = (const float*)d_in[6];
  const float* encWm    = (const float*)d_in[7];
  const float* encWs    = (const float*)d_in[8];
  const float* decWh    = (const float*)d_in[9];
  const float* dbh      = (const float*)d_in[10];
  const float* decWt    = (const float*)d_in[11];
  const float* dbt      = (const float*)d_in[12];
  const float* decWr    = (const float*)d_in[13];
  const float* dbr      = (const float*)d_in[14];
  const float* fcW      = (const float*)d_in[15];
  const float* fcb      = (const float*)d_in[16];
  const float* epsb     = (const float*)d_in[17];
  const int* srcA  = (const int*)d_in[18];
  const int* dstA  = (const int*)d_in[19];
  const int* etA   = (const int*)d_in[20];
  const int* asrcA = (const int*)d_in[21];
  const int* adstA = (const int*)d_in[22];
  const int* aetA  = (const int*)d_in[23];
  const int* rel_labels = (const int*)d_in[25];
  float* out = (float*)d_out;
  float* ws  = (float*)d_ws;

  k_prologue<<<1, 256, 0, stream>>>(rel_feat, rpW, rpb, decWr, dbr, ws, out);
  k_mega<<<BG, 256, 0, stream>>>(feat, Wrel, Wself, bvec, encWm, encWs, decWh, dbh,
                                 decWt, dbt, fcW, fcb, epsb, srcA, dstA, etA,
                                 asrcA, adstA, aetA, rel_labels, ws, out);
}

// Round 2
// 4007.959 us; speedup vs baseline: 1.4146x; 1.4146x over previous
//
#include <hip/hip_runtime.h>
#include <hip/hip_bf16.h>

// Problem constants (fixed by the reference)
#define NPG    128       // nodes per graph
#define EPG    1024      // edges per graph
#define BG     512       // graphs
#define PHI    0.1f
#define EPSV   1e-5f

// d_out float offsets: output[512] | g_out[512*192] | aug_g_out[512*192] | loss[1]
#define OUT_G    512
#define OUT_AUG  98816
#define OUT_LOSS 197120

// workspace float offsets
#define WS_EMB  0          // emb_rel [16*64]
#define WS_RELE 1024       // rel_e   [16*64]
#define WS_REPG 2048       // rep_g   [65536*192]

// Uniform-row FMA: 16x ds_read_b128 (broadcast) + 64 reg-resident FMAs, 4 accs.
#define ROW_FMA(hrptr, wcarr, a0, a1, a2, a3)                                  \
  {                                                                            \
    const float4* hr4_ = (const float4*)(hrptr);                               \
    _Pragma("unroll") for (int q_ = 0; q_ < 16; q_++) {                        \
      float4 h4_ = hr4_[q_];                                                   \
      a0 = fmaf(h4_.x, wcarr[4 * q_ + 0], a0);                                 \
      a1 = fmaf(h4_.y, wcarr[4 * q_ + 1], a1);                                 \
      a2 = fmaf(h4_.z, wcarr[4 * q_ + 2], a2);                                 \
      a3 = fmaf(h4_.w, wcarr[4 * q_ + 3], a3);                                 \
    }                                                                          \
  }

// ---------------------------------------------------------------------------
// Prologue: emb_rel = relu(rel_feat @ rel_proj_W + b); rel_e = relu(emb_rel @ dec_Wr + br)
// ---------------------------------------------------------------------------
__global__ __launch_bounds__(256) void k_prologue(
    const float* __restrict__ rel_feat, const float* __restrict__ rpW,
    const float* __restrict__ rpb, const float* __restrict__ dWr,
    const float* __restrict__ dbr, float* __restrict__ ws, float* __restrict__ out) {
  __shared__ float emb[16 * 64];
  int tid = threadIdx.x;
  for (int idx = tid; idx < 1024; idx += 256) {
    int r = idx >> 6, j = idx & 63;
    float s = rpb[j];
    for (int k = 0; k < 64; k++) s = fmaf(rel_feat[r * 64 + k], rpW[k * 64 + j], s);
    s = fmaxf(s, 0.f);
    emb[idx] = s;
    ws[WS_EMB + idx] = s;
  }
  __syncthreads();
  for (int idx = tid; idx < 1024; idx += 256) {
    int r = idx >> 6, j = idx & 63;
    float s = dbr[j];
    for (int k = 0; k < 64; k++) s = fmaf(emb[r * 64 + k], dWr[k * 64 + j], s);
    ws[WS_RELE + idx] = fmaxf(s, 0.f);
  }
  if (tid == 0) out[OUT_LOSS] = 0.f;
}

// ---------------------------------------------------------------------------
// Build compact per-graph edge list bucketed by etype (no padding) + deg^-1.
// entry: src(7b)<<12 | dst(7b)<<5 | et(4b)<<1 | 1
// ---------------------------------------------------------------------------
__device__ void build_elist(unsigned* elist, int* cnt, int* offs, float* deginv,
                            const unsigned* maskbits, int useMask,
                            const int* __restrict__ et_a, const int* __restrict__ src_a,
                            const int* __restrict__ dst_a, int ge, int gn, int tid) {
  if (tid < 16) cnt[tid] = 0;
  if (tid >= 128 && tid < 256) deginv[tid - 128] = 0.f;
  __syncthreads();
  for (int i = tid; i < EPG; i += 256) {
    int keep = useMask ? (int)((maskbits[i >> 5] >> (i & 31)) & 1u) : 1;
    if (keep) {
      atomicAdd(&cnt[et_a[ge + i]], 1);
      atomicAdd(&deginv[dst_a[ge + i] - gn], 1.f);
    }
  }
  __syncthreads();
  if (tid == 0) {
    int o = 0;
    for (int r = 0; r < 16; r++) { offs[r] = o; o += cnt[r]; }
    offs[16] = o;
  }
  __syncthreads();
  if (tid < 16) cnt[tid] = offs[tid];  // cursors
  if (tid >= 128 && tid < 256) {
    int v = tid - 128;
    deginv[v] = 1.0f / fmaxf(deginv[v], 1.0f);
  }
  __syncthreads();
  for (int i = tid; i < EPG; i += 256) {
    int keep = useMask ? (int)((maskbits[i >> 5] >> (i & 31)) & 1u) : 1;
    if (keep) {
      int r = et_a[ge + i];
      int pos = atomicAdd(&cnt[r], 1);
      elist[pos] = ((unsigned)(src_a[ge + i] - gn) << 12) |
                   ((unsigned)(dst_a[ge + i] - gn) << 5) | ((unsigned)r << 1) | 1u;
    }
  }
  __syncthreads();
}

// ---------------------------------------------------------------------------
// RGCN layer, transposed: lane = output column. Per relation bucket, the wave
// holds W[:,lane] in 64 VGPRs; per edge: uniform LDS row broadcast + 64 FMAs +
// conflict-free ds_add scatter. Then self-transform + finalize (32 nodes/wave).
// ---------------------------------------------------------------------------
__device__ void rgcn_layer(const float* hin, float* hout, const float* deginv,
                           const unsigned* elist, const int* offs,
                           const float* __restrict__ Wl, const float* __restrict__ Wsl,
                           const float* __restrict__ bl, int tid) {
  int lane = tid & 63, wave = tid >> 6;
  for (int i = tid; i < NPG * 64; i += 256) hout[i] = 0.f;
  __syncthreads();
  // ---- edge pass: wave w handles relations w, w+4, w+8, w+12 ----
  for (int r = wave; r < 16; r += 4) {
    int base = offs[r], end = offs[r + 1];
    if (base == end) continue;
    const float* __restrict__ W = Wl + (r << 12);
    float wc[64];
#pragma unroll
    for (int k = 0; k < 64; k++) wc[k] = W[(k << 6) + lane];  // column, coalesced
    for (int t = base; t < end; t++) {
      unsigned e = elist[t];
      int srcv = (int)((e >> 12) & 127);
      int dstv = (int)((e >> 5) & 127);
      float a0 = 0.f, a1 = 0.f, a2 = 0.f, a3 = 0.f;
      ROW_FMA(hin + (srcv << 6), wc, a0, a1, a2, a3);
      atomicAdd(&hout[(dstv << 6) + lane], (a0 + a1) + (a2 + a3));
    }
  }
  __syncthreads();
  // ---- self transform + finalize: wave w handles nodes [32w, 32w+32) ----
  {
    float wc[64];
#pragma unroll
    for (int k = 0; k < 64; k++) wc[k] = Wsl[(k << 6) + lane];
    float bj = bl[lane];
    for (int v = (wave << 5); v < (wave << 5) + 32; v++) {
      float a0 = 0.f, a1 = 0.f, a2 = 0.f, a3 = 0.f;
      ROW_FMA(hin + (v << 6), wc, a0, a1, a2, a3);
      float val = (a0 + a1) + (a2 + a3) + hout[(v << 6) + lane] * deginv[v] + bj;
      hout[(v << 6) + lane] = fmaxf(val, 0.f);
    }
  }
  __syncthreads();
}

// ---------------------------------------------------------------------------
// Dense 64x64, transposed (lane = column, W column in VGPRs, 32 nodes/wave).
// mode 0: out = acc ; 1: out = relu(acc+bias) ; 2: out += sqrt(exp(acc))*eps
// In-place (out==in) is safe: each row fully read before written, per wave.
// ---------------------------------------------------------------------------
__device__ void dense64(const float* in, float* out, const float* __restrict__ W,
                        const float* __restrict__ bias, int mode,
                        const float* __restrict__ epsbuf, int gn, int tid) {
  int lane = tid & 63, wave = tid >> 6;
  float wc[64];
#pragma unroll
  for (int k = 0; k < 64; k++) wc[k] = W[(k << 6) + lane];
  float bj = (mode == 1) ? bias[lane] : 0.f;
  for (int v = (wave << 5); v < (wave << 5) + 32; v++) {
    float a0 = 0.f, a1 = 0.f, a2 = 0.f, a3 = 0.f;
    ROW_FMA(in + (v << 6), wc, a0, a1, a2, a3);
    float a = (a0 + a1) + (a2 + a3);
    if (mode == 1) a = fmaxf(a + bj, 0.f);
    else if (mode == 2)
      a = out[(v << 6) + lane] + sqrtf(expf(a)) * epsbuf[((gn + v) << 6) + lane];
    out[(v << 6) + lane] = a;
  }
  __syncthreads();
}

// ---------------------------------------------------------------------------
// Column-parallel pool: dst[j] = (1/128) * sum_v hout[v][j]
// ---------------------------------------------------------------------------
__device__ void pool64(const float* hout, float* red, float* dst, int tid) {
  int j = tid & 63, grp = tid >> 6;
  float s = 0.f;
  for (int v = (grp << 5); v < (grp << 5) + 32; v++) s += hout[(v << 6) + j];
  red[tid] = s;
  __syncthreads();
  if (tid < 64)
    dst[tid] = (red[tid] + red[64 + tid] + red[128 + tid] + red[192 + tid]) * (1.f / 128.f);
  __syncthreads();
}

// ---------------------------------------------------------------------------
// Mega kernel: one workgroup per graph.
// ---------------------------------------------------------------------------
__global__ __launch_bounds__(256) void k_mega(
    const float* __restrict__ feat, const float* __restrict__ Wrel,
    const float* __restrict__ Wself, const float* __restrict__ bvec,
    const float* __restrict__ encWm, const float* __restrict__ encWs,
    const float* __restrict__ decWh, const float* __restrict__ dbh,
    const float* __restrict__ decWt, const float* __restrict__ dbt,
    const float* __restrict__ fcW, const float* __restrict__ fcb,
    const float* __restrict__ epsbuf,
    const int* __restrict__ srcA, const int* __restrict__ dstA, const int* __restrict__ etA,
    const int* __restrict__ asrcA, const int* __restrict__ adstA, const int* __restrict__ aetA,
    const int* __restrict__ rel_labels, float* __restrict__ ws, float* __restrict__ out) {
  __shared__ __align__(16) float buf0[NPG * 64];
  __shared__ __align__(16) float buf1[NPG * 64];
  __shared__ __align__(16) float relE[1024];
  __shared__ unsigned elist[EPG];
  __shared__ float deginv[NPG];
  __shared__ float red[256];
  __shared__ float ht[384];
  __shared__ float rgout[192];
  __shared__ unsigned maskbits[EPG / 32];
  __shared__ int cnt[16];
  __shared__ int offs[17];

  int g = blockIdx.x, tid = threadIdx.x;
  int gn = g * NPG, ge = g * EPG;
  float* repg = ws + WS_REPG;

  // stage rel_e into LDS (used much later; barriers intervene)
  for (int i = tid; i < 1024; i += 256) relE[i] = ws[WS_RELE + i];

  // ================= ORIG encode =================
  build_elist(elist, cnt, offs, deginv, maskbits, 0, etA, srcA, dstA, ge, gn, tid);
  for (int i = tid; i < NPG * 64; i += 256) buf0[i] = feat[gn * 64 + i];
  __syncthreads();
  for (int l = 0; l < 3; l++) {
    const float* hin = (l & 1) ? buf1 : buf0;
    float* hout = (l & 1) ? buf0 : buf1;
    rgcn_layer(hin, hout, deginv, elist, offs, Wrel + l * 65536, Wself + l * 4096,
               bvec + l * 64, tid);
    for (int i = tid; i < NPG * 64; i += 256)
      repg[(gn + (i >> 6)) * 192 + l * 64 + (i & 63)] = hout[i];
    pool64(hout, red, out + OUT_G + g * 192 + l * 64, tid);
  }
  // ================= AUG encode =================
  build_elist(elist, cnt, offs, deginv, maskbits, 0, aetA, asrcA, adstA, ge, gn, tid);
  for (int i = tid; i < NPG * 64; i += 256) buf0[i] = feat[gn * 64 + i];
  __syncthreads();
  for (int l = 0; l < 3; l++) {
    const float* hin = (l & 1) ? buf1 : buf0;
    float* hout = (l & 1) ? buf0 : buf1;
    rgcn_layer(hin, hout, deginv, elist, offs, Wrel + l * 65536, Wself + l * 4096,
               bvec + l * 64, tid);
    pool64(hout, red, out + OUT_AUG + g * 192 + l * 64, tid);
  }
  // aug_x in buf1; reload x (= rep_g layer 2) into buf0 (coalesced).
  for (int i = tid; i < NPG * 64; i += 256)
    buf0[i] = repg[(gn + (i >> 6)) * 192 + 128 + (i & 63)];
  __syncthreads();
  // ================= AdaIN (style into buf0); rotate-by-lane reads =================
  if (tid < NPG) {
    int v = tid;
    float s1 = 0.f, s2 = 0.f, t1 = 0.f, t2 = 0.f;
    for (int jj = 0; jj < 64; jj++) {
      int j = (v + jj) & 63;
      float x = buf0[(v << 6) + j];
      float y = buf1[(v << 6) + j];
      s1 += x; s2 += x * x; t1 += y; t2 += y * y;
    }
    float mc = s1 * (1.f / 64.f);
    float sc = sqrtf((s2 - 64.f * mc * mc) * (1.f / 63.f) + EPSV);
    float ms = t1 * (1.f / 64.f);
    float ss = sqrtf((t2 - 64.f * ms * ms) * (1.f / 63.f) + EPSV);
    float sca = ss / sc;
    for (int jj = 0; jj < 64; jj++) {
      int j = (v + jj) & 63;
      buf0[(v << 6) + j] = (buf0[(v << 6) + j] - mc) * sca + ms;
    }
  }
  __syncthreads();
  // ================= VAE + decoder node transforms =================
  dense64(buf0, buf1, encWm, nullptr, 0, nullptr, gn, tid);   // buf1 = z_mean
  dense64(buf0, buf1, encWs, nullptr, 2, epsbuf, gn, tid);    // buf1 = z
  dense64(buf1, buf0, decWh, dbh, 1, nullptr, gn, tid);       // buf0 = zh
  dense64(buf1, buf1, decWt, dbt, 1, nullptr, gn, tid);       // buf1 = zt (in-place safe)
  // ================= edge logits -> mask bits (rotate reads) =================
  for (int i = tid; i < EPG / 32; i += 256) maskbits[i] = 0u;
  __syncthreads();
  for (int i = tid; i < EPG; i += 256) {
    int s = srcA[ge + i] - gn, t = dstA[ge + i] - gn, r = etA[ge + i];
    int rot = (s + t) & 63;
    float lg = 0.f;
    for (int jj = 0; jj < 64; jj++) {
      int j = (rot + jj) & 63;
      lg = fmaf(buf0[(s << 6) + j] * buf1[(t << 6) + j], relE[(r << 6) + j], lg);
    }
    if (lg >= 0.5f) atomicOr(&maskbits[i >> 5], 1u << (i & 31));
  }
  __syncthreads();
  if (tid == 0) maskbits[0] |= 1u;  // root edge forced kept
  __syncthreads();
  // ================= RECON encode (masked edges skipped) =================
  build_elist(elist, cnt, offs, deginv, maskbits, 1, etA, srcA, dstA, ge, gn, tid);
  for (int i = tid; i < NPG * 64; i += 256) buf0[i] = feat[gn * 64 + i];
  __syncthreads();
  const float c1 = 1.0f / (65536.0f * 64.0f);  // mse: mean over N and D
  const float c2 = PHI / 65536.0f;             // style: PHI * mean over N
  for (int l = 0; l < 3; l++) {
    const float* hin = (l & 1) ? buf1 : buf0;
    float* hout = (l & 1) ? buf0 : buf1;
    float* gbuf = (l & 1) ? buf1 : buf0;  // hin buffer, dead after layer
    rgcn_layer(hin, hout, deginv, elist, offs, Wrel + l * 65536, Wself + l * 4096,
               bvec + l * 64, tid);
    // pool -> rgout[l]; head/tail rows -> ht
    {
      int j = tid & 63, grp = tid >> 6;
      float s = 0.f;
      for (int v = (grp << 5); v < (grp << 5) + 32; v++) s += hout[(v << 6) + j];
      red[tid] = s;
      __syncthreads();
      if (tid < 64)
        rgout[l * 64 + tid] =
            (red[tid] + red[64 + tid] + red[128 + tid] + red[192 + tid]) * (1.f / 128.f);
      if (tid >= 64 && tid < 192) {
        int i2 = tid - 64;  // rows 0 (head) and 1 (tail)
        ht[(l * 2 + (i2 >> 6)) * 64 + (i2 & 63)] = hout[((i2 >> 6) << 6) + (i2 & 63)];
      }
      __syncthreads();
    }
    // reload rep_g layer l into gbuf (coalesced), then per-node loss stats
    for (int i = tid; i < NPG * 64; i += 256)
      gbuf[i] = repg[(gn + (i >> 6)) * 192 + l * 64 + (i & 63)];
    __syncthreads();
    if (tid < NPG) {
      int v = tid;
      float mse = 0.f, a1 = 0.f, a2 = 0.f, b1 = 0.f, b2 = 0.f;
      for (int jj = 0; jj < 64; jj++) {
        int j = (v + jj) & 63;
        float rc = hout[(v << 6) + j];
        float gg = gbuf[(v << 6) + j];
        float d = rc - gg;
        mse += d * d; a1 += rc; a2 += rc * rc; b1 += gg; b2 += gg * gg;
      }
      float mr = a1 * (1.f / 64.f), mg = b1 * (1.f / 64.f);
      float sr = sqrtf((a2 - 64.f * mr * mr) * (1.f / 63.f) + EPSV);
      float sg = sqrtf((b2 - 64.f * mg * mg) * (1.f / 63.f) + EPSV);
      float style = (mr - mg) * (mr - mg) + (sr - sg) * (sr - sg);
      red[v] = mse * c1 + style * c2;
    }
    __syncthreads();
    if (tid < 64) {
      float x = red[tid] + red[tid + 64];
#pragma unroll
      for (int o = 32; o > 0; o >>= 1) x += __shfl_down(x, o);
      if (tid == 0) atomicAdd(&out[OUT_LOSS], x);
    }
    __syncthreads();
  }
  // ================= final fc output =================
  if (tid < 64) {
    int rl = rel_labels[g];
    const float* emb = ws + WS_EMB + rl * 64;
    float s = 0.f;
    for (int p = 0; p < 10; p++) {
      int i = p * 64 + tid;
      float gr;
      if (i < 192) gr = rgout[i];
      else if (i < 384) { int i2 = i - 192; gr = ht[((i2 >> 6) * 2 + 0) * 64 + (i2 & 63)]; }
      else if (i < 576) { int i2 = i - 384; gr = ht[((i2 >> 6) * 2 + 1) * 64 + (i2 & 63)]; }
      else gr = emb[i - 576];
      s = fmaf(gr, fcW[i], s);
    }
#pragma unroll
    for (int o = 32; o > 0; o >>= 1) s += __shfl_down(s, o);
    if (tid == 0) out[g] = s + fcb[0];
  }
}

extern "C" void kernel_launch(void* const* d_in, const int* in_sizes, int n_in,
                              void* d_out, int out_size, void* d_ws, size_t ws_size,
                              hipStream_t stream) {
  const float* feat     = (const float*)d_in[0];
  const float* rel_feat = (const float*)d_in[1];
  const float* rpW      = (const float*)d_in[2];
  const float* rpb      = (const float*)d_in[3];
  const float* Wrel     = (const float*)d_in[4];
  const float* Wself    = (const float*)d_in[5];
  const float* bvec     = (const float*)d_in[6];
  const float* encWm    = (const float*)d_in[7];
  const float* encWs    = (const float*)d_in[8];
  const float* decWh    = (const float*)d_in[9];
  const float* dbh      = (const float*)d_in[10];
  const float* decWt    = (const float*)d_in[11];
  const float* dbt      = (const float*)d_in[12];
  const float* decWr    = (const float*)d_in[13];
  const float* dbr      = (const float*)d_in[14];
  const float* fcW      = (const float*)d_in[15];
  const float* fcb      = (const float*)d_in[16];
  const float* epsb     = (const float*)d_in[17];
  const int* srcA  = (const int*)d_in[18];
  const int* dstA  = (const int*)d_in[19];
  const int* etA   = (const int*)d_in[20];
  const int* asrcA = (const int*)d_in[21];
  const int* adstA = (const int*)d_in[22];
  const int* aetA  = (const int*)d_in[23];
  const int* rel_labels = (const int*)d_in[25];
  float* out = (float*)d_out;
  float* ws  = (float*)d_ws;

  k_prologue<<<1, 256, 0, stream>>>(rel_feat, rpW, rpb, decWr, dbr, ws, out);
  k_mega<<<BG, 256, 0, stream>>>(feat, Wrel, Wself, bvec, encWm, encWs, decWh, dbh,
                                 decWt, dbt, fcW, fcb, epsb, srcA, dstA, etA,
                                 asrcA, adstA, aetA, rel_labels, ws, out);
}

// Round 3
// 3664.594 us; speedup vs baseline: 1.5471x; 1.0937x over previous
//
#include <hip/hip_runtime.h>
#include <hip/hip_bf16.h>

// Problem constants (fixed by the reference)
#define NPG    128       // nodes per graph
#define EPG    1024      // edges per graph
#define BG     512       // graphs
#define PHI    0.1f
#define EPSV   1e-5f

// d_out float offsets: output[512] | g_out[512*192] | aug_g_out[512*192] | loss[1]
#define OUT_G    512
#define OUT_AUG  98816
#define OUT_LOSS 197120

// workspace float offsets
#define WS_EMB  0          // emb_rel [16*64]
#define WS_RELE 1024       // rel_e   [16*64]
#define WS_REPG 2048       // rep_g   [65536*192]

// ---------------------------------------------------------------------------
// Prologue (transposed): emb_rel = relu(rel_feat @ rpW + rpb);
// rel_e = relu(emb_rel @ dWr + dbr). lane = output column, W column in VGPRs.
// ---------------------------------------------------------------------------
__global__ __launch_bounds__(256) void k_prologue(
    const float* __restrict__ rel_feat, const float* __restrict__ rpW,
    const float* __restrict__ rpb, const float* __restrict__ dWr,
    const float* __restrict__ dbr, float* __restrict__ ws, float* __restrict__ out) {
  __shared__ __align__(16) float emb[1024];
  int tid = threadIdx.x, lane = tid & 63, wave = tid >> 6;
  {
    float wc[64];
#pragma unroll
    for (int k = 0; k < 64; k++) wc[k] = rpW[(k << 6) + lane];
    float bj = rpb[lane];
    for (int r = (wave << 2); r < (wave << 2) + 4; r++) {
      const float4* p = (const float4*)(rel_feat + (r << 6));
      float a0 = 0.f, a1 = 0.f, a2 = 0.f, a3 = 0.f;
#pragma unroll
      for (int q = 0; q < 16; q++) {
        float4 h = p[q];
        a0 = fmaf(h.x, wc[4 * q + 0], a0);
        a1 = fmaf(h.y, wc[4 * q + 1], a1);
        a2 = fmaf(h.z, wc[4 * q + 2], a2);
        a3 = fmaf(h.w, wc[4 * q + 3], a3);
      }
      float s = fmaxf((a0 + a1) + (a2 + a3) + bj, 0.f);
      emb[(r << 6) + lane] = s;
      ws[WS_EMB + (r << 6) + lane] = s;
    }
  }
  __syncthreads();
  {
    float wc[64];
#pragma unroll
    for (int k = 0; k < 64; k++) wc[k] = dWr[(k << 6) + lane];
    float bj = dbr[lane];
    for (int r = (wave << 2); r < (wave << 2) + 4; r++) {
      const float4* p = (const float4*)(emb + (r << 6));
      float a0 = 0.f, a1 = 0.f, a2 = 0.f, a3 = 0.f;
#pragma unroll
      for (int q = 0; q < 16; q++) {
        float4 h = p[q];
        a0 = fmaf(h.x, wc[4 * q + 0], a0);
        a1 = fmaf(h.y, wc[4 * q + 1], a1);
        a2 = fmaf(h.z, wc[4 * q + 2], a2);
        a3 = fmaf(h.w, wc[4 * q + 3], a3);
      }
      ws[WS_RELE + (r << 6) + lane] = fmaxf((a0 + a1) + (a2 + a3) + bj, 0.f);
    }
  }
  if (tid == 0) out[OUT_LOSS] = 0.f;
}

// ---------------------------------------------------------------------------
// Build compact per-graph edge list bucketed by etype + deg^-1 + greedy
// wave assignment (balance bucket sizes over 4 waves).
// entry: (src 7b << 7) | dst 7b   (etype implicit from bucket)
// ---------------------------------------------------------------------------
__device__ void build_elist(unsigned* elist, int* cnt, int* offs, int* asg, float* deginv,
                            const unsigned* maskbits, int useMask,
                            const int* __restrict__ et_a, const int* __restrict__ src_a,
                            const int* __restrict__ dst_a, int ge, int gn, int tid) {
  if (tid < 16) cnt[tid] = 0;
  if (tid >= 128 && tid < 256) deginv[tid - 128] = 0.f;
  __syncthreads();
  for (int i = tid; i < EPG; i += 256) {
    int keep = useMask ? (int)((maskbits[i >> 5] >> (i & 31)) & 1u) : 1;
    if (keep) {
      atomicAdd(&cnt[et_a[ge + i]], 1);
      atomicAdd(&deginv[dst_a[ge + i] - gn], 1.f);
    }
  }
  __syncthreads();
  if (tid == 0) {
    int o = 0;
    for (int r = 0; r < 16; r++) { offs[r] = o; o += cnt[r]; }
    offs[16] = o;
    // greedy: largest bucket to least-loaded wave
    int load[4] = {0, 0, 0, 0};
    unsigned used = 0;
    for (int s = 0; s < 16; s++) {
      int best = 0, bc = -1;
      for (int r = 0; r < 16; r++)
        if (!((used >> r) & 1) && cnt[r] > bc) { bc = cnt[r]; best = r; }
      used |= 1u << best;
      int bw = 0;
      for (int w = 1; w < 4; w++) if (load[w] < load[bw]) bw = w;
      asg[best] = bw;
      load[bw] += bc;
    }
  }
  __syncthreads();
  if (tid < 16) cnt[tid] = offs[tid];  // cursors
  if (tid >= 128 && tid < 256) {
    int v = tid - 128;
    deginv[v] = 1.0f / fmaxf(deginv[v], 1.0f);
  }
  __syncthreads();
  for (int i = tid; i < EPG; i += 256) {
    int keep = useMask ? (int)((maskbits[i >> 5] >> (i & 31)) & 1u) : 1;
    if (keep) {
      int r = et_a[ge + i];
      int pos = atomicAdd(&cnt[r], 1);
      elist[pos] = ((unsigned)(src_a[ge + i] - gn) << 7) | (unsigned)(dst_a[ge + i] - gn);
    }
  }
  __syncthreads();
}

// ---------------------------------------------------------------------------
// RGCN layer: lane = output column, W[:,lane] in 64 VGPRs per relation bucket.
// Edge descriptors via readlane (no memory latency); 2-edge unroll for MLP.
// ---------------------------------------------------------------------------
__device__ void rgcn_layer(const float* hin, float* hout, const float* deginv,
                           const unsigned* elist, const int* offs, const int* asg,
                           const float* __restrict__ Wl, const float* __restrict__ Wsl,
                           const float* __restrict__ bl, int tid) {
  int lane = tid & 63, wave = tid >> 6;
  for (int i = tid; i < 2048; i += 256) ((float4*)hout)[i] = make_float4(0.f, 0.f, 0.f, 0.f);
  __syncthreads();
  // ---- edge pass ----
  for (int r = 0; r < 16; r++) {
    if (asg[r] != wave) continue;
    int base = offs[r], n = offs[r + 1] - base;
    if (n == 0) continue;
    const float* __restrict__ W = Wl + (r << 12);
    float wc[64];
#pragma unroll
    for (int k = 0; k < 64; k++) wc[k] = W[(k << 6) + lane];  // column, coalesced
    for (int c = 0; c < n; c += 64) {
      unsigned epack = elist[base + c + lane];  // 64 edges in the wave's lanes
      int m = (n - c < 64) ? (n - c) : 64;
      int i = 0;
      for (; i + 2 <= m; i += 2) {
        unsigned e0 = __builtin_amdgcn_readlane(epack, i);
        unsigned e1 = __builtin_amdgcn_readlane(epack, i + 1);
        const float4* p0 = (const float4*)(hin + ((e0 >> 7) << 6));
        const float4* p1 = (const float4*)(hin + ((e1 >> 7) << 6));
        float a0 = 0.f, a1 = 0.f, a2 = 0.f, a3 = 0.f;
        float b0 = 0.f, b1 = 0.f, b2 = 0.f, b3 = 0.f;
#pragma unroll
        for (int q = 0; q < 16; q++) {
          float4 h0 = p0[q];
          float4 h1 = p1[q];
          a0 = fmaf(h0.x, wc[4 * q + 0], a0); b0 = fmaf(h1.x, wc[4 * q + 0], b0);
          a1 = fmaf(h0.y, wc[4 * q + 1], a1); b1 = fmaf(h1.y, wc[4 * q + 1], b1);
          a2 = fmaf(h0.z, wc[4 * q + 2], a2); b2 = fmaf(h1.z, wc[4 * q + 2], b2);
          a3 = fmaf(h0.w, wc[4 * q + 3], a3); b3 = fmaf(h1.w, wc[4 * q + 3], b3);
        }
        atomicAdd(&hout[((e0 & 127) << 6) + lane], (a0 + a1) + (a2 + a3));
        atomicAdd(&hout[((e1 & 127) << 6) + lane], (b0 + b1) + (b2 + b3));
      }
      if (i < m) {
        unsigned e0 = __builtin_amdgcn_readlane(epack, i);
        const float4* p0 = (const float4*)(hin + ((e0 >> 7) << 6));
        float a0 = 0.f, a1 = 0.f, a2 = 0.f, a3 = 0.f;
#pragma unroll
        for (int q = 0; q < 16; q++) {
          float4 h0 = p0[q];
          a0 = fmaf(h0.x, wc[4 * q + 0], a0);
          a1 = fmaf(h0.y, wc[4 * q + 1], a1);
          a2 = fmaf(h0.z, wc[4 * q + 2], a2);
          a3 = fmaf(h0.w, wc[4 * q + 3], a3);
        }
        atomicAdd(&hout[((e0 & 127) << 6) + lane], (a0 + a1) + (a2 + a3));
      }
    }
  }
  __syncthreads();
  // ---- self transform + finalize: wave w handles nodes [32w, 32w+32) ----
  {
    float wc[64];
#pragma unroll
    for (int k = 0; k < 64; k++) wc[k] = Wsl[(k << 6) + lane];
    float bj = bl[lane];
    for (int v = (wave << 5); v < (wave << 5) + 32; v++) {
      const float4* p = (const float4*)(hin + (v << 6));
      float a0 = 0.f, a1 = 0.f, a2 = 0.f, a3 = 0.f;
#pragma unroll
      for (int q = 0; q < 16; q++) {
        float4 h = p[q];
        a0 = fmaf(h.x, wc[4 * q + 0], a0);
        a1 = fmaf(h.y, wc[4 * q + 1], a1);
        a2 = fmaf(h.z, wc[4 * q + 2], a2);
        a3 = fmaf(h.w, wc[4 * q + 3], a3);
      }
      float val = (a0 + a1) + (a2 + a3) + hout[(v << 6) + lane] * deginv[v] + bj;
      hout[(v << 6) + lane] = fmaxf(val, 0.f);
    }
  }
  __syncthreads();
}

// ---------------------------------------------------------------------------
// Dense 64x64, transposed (lane = column, W column in VGPRs, 32 nodes/wave).
// mode 0: out = acc ; 1: out = relu(acc+bias) ; 2: out += sqrt(exp(acc))*eps
// ---------------------------------------------------------------------------
__device__ void dense64(const float* in, float* out, const float* __restrict__ W,
                        const float* __restrict__ bias, int mode,
                        const float* __restrict__ epsbuf, int gn, int tid) {
  int lane = tid & 63, wave = tid >> 6;
  float wc[64];
#pragma unroll
  for (int k = 0; k < 64; k++) wc[k] = W[(k << 6) + lane];
  float bj = (mode == 1) ? bias[lane] : 0.f;
  for (int v = (wave << 5); v < (wave << 5) + 32; v++) {
    const float4* p = (const float4*)(in + (v << 6));
    float a0 = 0.f, a1 = 0.f, a2 = 0.f, a3 = 0.f;
#pragma unroll
    for (int q = 0; q < 16; q++) {
      float4 h = p[q];
      a0 = fmaf(h.x, wc[4 * q + 0], a0);
      a1 = fmaf(h.y, wc[4 * q + 1], a1);
      a2 = fmaf(h.z, wc[4 * q + 2], a2);
      a3 = fmaf(h.w, wc[4 * q + 3], a3);
    }
    float a = (a0 + a1) + (a2 + a3);
    if (mode == 1) a = fmaxf(a + bj, 0.f);
    else if (mode == 2)
      a = out[(v << 6) + lane] + sqrtf(expf(a)) * epsbuf[((gn + v) << 6) + lane];
    out[(v << 6) + lane] = a;
  }
  __syncthreads();
}

// ---------------------------------------------------------------------------
// Column-parallel pool: dst[j] = (1/128) * sum_v hout[v][j]
// ---------------------------------------------------------------------------
__device__ void pool64(const float* hout, float* red, float* dst, int tid) {
  int j = tid & 63, grp = tid >> 6;
  float s = 0.f;
  for (int v = (grp << 5); v < (grp << 5) + 32; v++) s += hout[(v << 6) + j];
  red[tid] = s;
  __syncthreads();
  if (tid < 64)
    dst[tid] = (red[tid] + red[64 + tid] + red[128 + tid] + red[192 + tid]) * (1.f / 128.f);
  __syncthreads();
}

// ---------------------------------------------------------------------------
// Mega kernel: one workgroup per graph.
// ---------------------------------------------------------------------------
__global__ __launch_bounds__(256) void k_mega(
    const float* __restrict__ feat, const float* __restrict__ Wrel,
    const float* __restrict__ Wself, const float* __restrict__ bvec,
    const float* __restrict__ encWm, const float* __restrict__ encWs,
    const float* __restrict__ decWh, const float* __restrict__ dbh,
    const float* __restrict__ decWt, const float* __restrict__ dbt,
    const float* __restrict__ fcW, const float* __restrict__ fcb,
    const float* __restrict__ epsbuf,
    const int* __restrict__ srcA, const int* __restrict__ dstA, const int* __restrict__ etA,
    const int* __restrict__ asrcA, const int* __restrict__ adstA, const int* __restrict__ aetA,
    const int* __restrict__ rel_labels, float* __restrict__ ws, float* __restrict__ out) {
  __shared__ __align__(16) float buf0[NPG * 64];
  __shared__ __align__(16) float buf1[NPG * 64];
  __shared__ __align__(16) unsigned elist[EPG + 64];  // also reused to stage rel_e
  __shared__ float deginv[NPG];
  __shared__ float red[256];
  __shared__ float ht[384];
  __shared__ float rgout[192];
  __shared__ unsigned maskbits[EPG / 32];
  __shared__ int cnt[16];
  __shared__ int offs[17];
  __shared__ int asg[16];

  int g = blockIdx.x, tid = threadIdx.x;
  int gn = g * NPG, ge = g * EPG;
  float* repg = ws + WS_REPG;

  // ================= ORIG encode =================
  build_elist(elist, cnt, offs, asg, deginv, maskbits, 0, etA, srcA, dstA, ge, gn, tid);
  for (int i = tid; i < 2048; i += 256)
    ((float4*)buf0)[i] = ((const float4*)(feat + gn * 64))[i];
  __syncthreads();
  for (int l = 0; l < 3; l++) {
    const float* hin = (l & 1) ? buf1 : buf0;
    float* hout = (l & 1) ? buf0 : buf1;
    rgcn_layer(hin, hout, deginv, elist, offs, asg, Wrel + l * 65536, Wself + l * 4096,
               bvec + l * 64, tid);
    for (int i = tid; i < 2048; i += 256) {
      int v = i >> 4, q = i & 15;
      ((float4*)repg)[(gn + v) * 48 + l * 16 + q] = ((const float4*)hout)[i];
    }
    pool64(hout, red, out + OUT_G + g * 192 + l * 64, tid);
  }
  // ================= AUG encode =================
  build_elist(elist, cnt, offs, asg, deginv, maskbits, 0, aetA, asrcA, adstA, ge, gn, tid);
  for (int i = tid; i < 2048; i += 256)
    ((float4*)buf0)[i] = ((const float4*)(feat + gn * 64))[i];
  __syncthreads();
  for (int l = 0; l < 3; l++) {
    const float* hin = (l & 1) ? buf1 : buf0;
    float* hout = (l & 1) ? buf0 : buf1;
    rgcn_layer(hin, hout, deginv, elist, offs, asg, Wrel + l * 65536, Wself + l * 4096,
               bvec + l * 64, tid);
    pool64(hout, red, out + OUT_AUG + g * 192 + l * 64, tid);
  }
  // aug_x in buf1; reload x (= rep_g layer 2) into buf0 (coalesced).
  for (int i = tid; i < 2048; i += 256) {
    int v = i >> 4, q = i & 15;
    ((float4*)buf0)[i] = ((const float4*)repg)[(gn + v) * 48 + 32 + q];
  }
  __syncthreads();
  // ================= AdaIN (style into buf0); rotate-by-lane reads =================
  if (tid < NPG) {
    int v = tid;
    float s1 = 0.f, s2 = 0.f, t1 = 0.f, t2 = 0.f;
    for (int jj = 0; jj < 64; jj++) {
      int j = (v + jj) & 63;
      float x = buf0[(v << 6) + j];
      float y = buf1[(v << 6) + j];
      s1 += x; s2 += x * x; t1 += y; t2 += y * y;
    }
    float mc = s1 * (1.f / 64.f);
    float sc = sqrtf((s2 - 64.f * mc * mc) * (1.f / 63.f) + EPSV);
    float ms = t1 * (1.f / 64.f);
    float ss = sqrtf((t2 - 64.f * ms * ms) * (1.f / 63.f) + EPSV);
    float sca = ss / sc;
    for (int jj = 0; jj < 64; jj++) {
      int j = (v + jj) & 63;
      buf0[(v << 6) + j] = (buf0[(v << 6) + j] - mc) * sca + ms;
    }
  }
  __syncthreads();
  // ================= VAE + decoder node transforms =================
  dense64(buf0, buf1, encWm, nullptr, 0, nullptr, gn, tid);   // buf1 = z_mean
  dense64(buf0, buf1, encWs, nullptr, 2, epsbuf, gn, tid);    // buf1 = z
  dense64(buf1, buf0, decWh, dbh, 1, nullptr, gn, tid);       // buf0 = zh
  dense64(buf1, buf1, decWt, dbt, 1, nullptr, gn, tid);       // buf1 = zt (in-place safe)
  // ================= stage rel_e into dead elist space =================
  float* relEl = (float*)elist;
  for (int i = tid; i < 1024; i += 256) relEl[i] = ws[WS_RELE + i];
  for (int i = tid; i < EPG / 32; i += 256) maskbits[i] = 0u;
  __syncthreads();
  // ================= edge logits -> mask bits (rotate reads) =================
  for (int i = tid; i < EPG; i += 256) {
    int s = srcA[ge + i] - gn, t = dstA[ge + i] - gn, r = etA[ge + i];
    int rot = (s + t) & 63;
    float lg = 0.f;
    for (int jj = 0; jj < 64; jj++) {
      int j = (rot + jj) & 63;
      lg = fmaf(buf0[(s << 6) + j] * buf1[(t << 6) + j], relEl[(r << 6) + j], lg);
    }
    if (lg >= 0.5f) atomicOr(&maskbits[i >> 5], 1u << (i & 31));
  }
  __syncthreads();
  if (tid == 0) maskbits[0] |= 1u;  // root edge forced kept
  __syncthreads();
  // ================= RECON encode (masked edges skipped) =================
  build_elist(elist, cnt, offs, asg, deginv, maskbits, 1, etA, srcA, dstA, ge, gn, tid);
  for (int i = tid; i < 2048; i += 256)
    ((float4*)buf0)[i] = ((const float4*)(feat + gn * 64))[i];
  __syncthreads();
  const float c1 = 1.0f / (65536.0f * 64.0f);  // mse: mean over N and D
  const float c2 = PHI / 65536.0f;             // style: PHI * mean over N
  for (int l = 0; l < 3; l++) {
    const float* hin = (l & 1) ? buf1 : buf0;
    float* hout = (l & 1) ? buf0 : buf1;
    float* gbuf = (l & 1) ? buf1 : buf0;  // hin buffer, dead after layer
    rgcn_layer(hin, hout, deginv, elist, offs, asg, Wrel + l * 65536, Wself + l * 4096,
               bvec + l * 64, tid);
    // pool -> rgout[l]; head/tail rows -> ht
    {
      int j = tid & 63, grp = tid >> 6;
      float s = 0.f;
      for (int v = (grp << 5); v < (grp << 5) + 32; v++) s += hout[(v << 6) + j];
      red[tid] = s;
      __syncthreads();
      if (tid < 64)
        rgout[l * 64 + tid] =
            (red[tid] + red[64 + tid] + red[128 + tid] + red[192 + tid]) * (1.f / 128.f);
      if (tid >= 64 && tid < 192) {
        int i2 = tid - 64;  // rows 0 (head) and 1 (tail)
        ht[(l * 2 + (i2 >> 6)) * 64 + (i2 & 63)] = hout[((i2 >> 6) << 6) + (i2 & 63)];
      }
      __syncthreads();
    }
    // reload rep_g layer l into gbuf (coalesced), then per-node loss stats
    for (int i = tid; i < 2048; i += 256) {
      int v = i >> 4, q = i & 15;
      ((float4*)gbuf)[i] = ((const float4*)repg)[(gn + v) * 48 + l * 16 + q];
    }
    __syncthreads();
    if (tid < NPG) {
      int v = tid;
      float mse = 0.f, a1 = 0.f, a2 = 0.f, b1 = 0.f, b2 = 0.f;
      for (int jj = 0; jj < 64; jj++) {
        int j = (v + jj) & 63;
        float rc = hout[(v << 6) + j];
        float gg = gbuf[(v << 6) + j];
        float d = rc - gg;
        mse += d * d; a1 += rc; a2 += rc * rc; b1 += gg; b2 += gg * gg;
      }
      float mr = a1 * (1.f / 64.f), mg = b1 * (1.f / 64.f);
      float sr = sqrtf((a2 - 64.f * mr * mr) * (1.f / 63.f) + EPSV);
      float sg = sqrtf((b2 - 64.f * mg * mg) * (1.f / 63.f) + EPSV);
      float style = (mr - mg) * (mr - mg) + (sr - sg) * (sr - sg);
      red[v] = mse * c1 + style * c2;
    }
    __syncthreads();
    if (tid < 64) {
      float x = red[tid] + red[tid + 64];
#pragma unroll
      for (int o = 32; o > 0; o >>= 1) x += __shfl_down(x, o);
      if (tid == 0) atomicAdd(&out[OUT_LOSS], x);
    }
    __syncthreads();
  }
  // ================= final fc output =================
  if (tid < 64) {
    int rl = rel_labels[g];
    const float* emb = ws + WS_EMB + rl * 64;
    float s = 0.f;
    for (int p = 0; p < 10; p++) {
      int i = p * 64 + tid;
      float gr;
      if (i < 192) gr = rgout[i];
      else if (i < 384) { int i2 = i - 192; gr = ht[((i2 >> 6) * 2 + 0) * 64 + (i2 & 63)]; }
      else if (i < 576) { int i2 = i - 384; gr = ht[((i2 >> 6) * 2 + 1) * 64 + (i2 & 63)]; }
      else gr = emb[i - 576];
      s = fmaf(gr, fcW[i], s);
    }
#pragma unroll
    for (int o = 32; o > 0; o >>= 1) s += __shfl_down(s, o);
    if (tid == 0) out[g] = s + fcb[0];
  }
}

extern "C" void kernel_launch(void* const* d_in, const int* in_sizes, int n_in,
                              void* d_out, int out_size, void* d_ws, size_t ws_size,
                              hipStream_t stream) {
  const float* feat     = (const float*)d_in[0];
  const float* rel_feat = (const float*)d_in[1];
  const float* rpW      = (const float*)d_in[2];
  const float* rpb      = (const float*)d_in[3];
  const float* Wrel     = (const float*)d_in[4];
  const float* Wself    = (const float*)d_in[5];
  const float* bvec     = (const float*)d_in[6];
  const float* encWm    = (const float*)d_in[7];
  const float* encWs    = (const float*)d_in[8];
  const float* decWh    = (const float*)d_in[9];
  const float* dbh      = (const float*)d_in[10];
  const float* decWt    = (const float*)d_in[11];
  const float* dbt      = (const float*)d_in[12];
  const float* decWr    = (const float*)d_in[13];
  const float* dbr      = (const float*)d_in[14];
  const float* fcW      = (const float*)d_in[15];
  const float* fcb      = (const float*)d_in[16];
  const float* epsb     = (const float*)d_in[17];
  const int* srcA  = (const int*)d_in[18];
  const int* dstA  = (const int*)d_in[19];
  const int* etA   = (const int*)d_in[20];
  const int* asrcA = (const int*)d_in[21];
  const int* adstA = (const int*)d_in[22];
  const int* aetA  = (const int*)d_in[23];
  const int* rel_labels = (const int*)d_in[25];
  float* out = (float*)d_out;
  float* ws  = (float*)d_ws;

  k_prologue<<<1, 256, 0, stream>>>(rel_feat, rpW, rpb, decWr, dbr, ws, out);
  k_mega<<<BG, 256, 0, stream>>>(feat, Wrel, Wself, bvec, encWm, encWs, decWh, dbh,
                                 decWt, dbt, fcW, fcb, epsb, srcA, dstA, etA,
                                 asrcA, adstA, aetA, rel_labels, ws, out);
}

// Round 4
// 2752.962 us; speedup vs baseline: 2.0594x; 1.3311x over previous
//
#include <hip/hip_runtime.h>
#include <hip/hip_bf16.h>

// Problem constants (fixed by the reference)
#define NPG    128       // nodes per graph
#define EPG    1024      // edges per graph
#define BG     512       // graphs
#define NT     512       // threads per block (8 waves)
#define NW     8         // waves per block
#define PHI    0.1f
#define EPSV   1e-5f

// d_out float offsets: output[512] | g_out[512*192] | aug_g_out[512*192] | loss[1]
#define OUT_G    512
#define OUT_AUG  98816
#define OUT_LOSS 197120

// workspace float offsets
#define WS_EMB  0          // emb_rel [16*64]
#define WS_RELE 1024       // rel_e   [16*64]
#define WS_REPG 2048       // rep_g   [65536*192]

// Uniform-row FMA: 16x ds_read_b128 (broadcast) + 64 reg-resident FMAs, 4 accs.
#define ROW_FMA(hrptr, wcarr, a0, a1, a2, a3)                                  \
  {                                                                            \
    const float4* hr4_ = (const float4*)(hrptr);                               \
    _Pragma("unroll") for (int q_ = 0; q_ < 16; q_++) {                        \
      float4 h4_ = hr4_[q_];                                                   \
      a0 = fmaf(h4_.x, wcarr[4 * q_ + 0], a0);                                 \
      a1 = fmaf(h4_.y, wcarr[4 * q_ + 1], a1);                                 \
      a2 = fmaf(h4_.z, wcarr[4 * q_ + 2], a2);                                 \
      a3 = fmaf(h4_.w, wcarr[4 * q_ + 3], a3);                                 \
    }                                                                          \
  }

// ---------------------------------------------------------------------------
// Prologue (transposed): emb_rel = relu(rel_feat @ rpW + rpb);
// rel_e = relu(emb_rel @ dWr + dbr). lane = output column, W column in VGPRs.
// ---------------------------------------------------------------------------
__global__ __launch_bounds__(256) void k_prologue(
    const float* __restrict__ rel_feat, const float* __restrict__ rpW,
    const float* __restrict__ rpb, const float* __restrict__ dWr,
    const float* __restrict__ dbr, float* __restrict__ ws, float* __restrict__ out) {
  __shared__ __align__(16) float emb[1024];
  int tid = threadIdx.x, lane = tid & 63, wave = tid >> 6;
  {
    float wc[64];
#pragma unroll
    for (int k = 0; k < 64; k++) wc[k] = rpW[(k << 6) + lane];
    float bj = rpb[lane];
    for (int r = (wave << 2); r < (wave << 2) + 4; r++) {
      float a0 = 0.f, a1 = 0.f, a2 = 0.f, a3 = 0.f;
      ROW_FMA(rel_feat + (r << 6), wc, a0, a1, a2, a3);
      float s = fmaxf((a0 + a1) + (a2 + a3) + bj, 0.f);
      emb[(r << 6) + lane] = s;
      ws[WS_EMB + (r << 6) + lane] = s;
    }
  }
  __syncthreads();
  {
    float wc[64];
#pragma unroll
    for (int k = 0; k < 64; k++) wc[k] = dWr[(k << 6) + lane];
    float bj = dbr[lane];
    for (int r = (wave << 2); r < (wave << 2) + 4; r++) {
      float a0 = 0.f, a1 = 0.f, a2 = 0.f, a3 = 0.f;
      ROW_FMA(emb + (r << 6), wc, a0, a1, a2, a3);
      ws[WS_RELE + (r << 6) + lane] = fmaxf((a0 + a1) + (a2 + a3) + bj, 0.f);
    }
  }
  if (tid == 0) out[OUT_LOSS] = 0.f;
}

// ---------------------------------------------------------------------------
// Build compact per-graph edge list bucketed by etype + clipped degree and
// its reciprocal + greedy wave assignment (balance bucket sizes over 8 waves).
// entry: (src 7b << 7) | dst 7b   (etype implicit from bucket)
// ---------------------------------------------------------------------------
__device__ void build_elist(unsigned* elist, int* cnt, int* offs, int* asg,
                            float* degc, float* dinv,
                            const unsigned* maskbits, int useMask,
                            const int* __restrict__ et_a, const int* __restrict__ src_a,
                            const int* __restrict__ dst_a, int ge, int gn, int tid) {
  if (tid < 16) cnt[tid] = 0;
  if (tid >= 128 && tid < 256) degc[tid - 128] = 0.f;
  __syncthreads();
  for (int i = tid; i < EPG; i += NT) {
    int keep = useMask ? (int)((maskbits[i >> 5] >> (i & 31)) & 1u) : 1;
    if (keep) {
      atomicAdd(&cnt[et_a[ge + i]], 1);
      atomicAdd(&degc[dst_a[ge + i] - gn], 1.f);
    }
  }
  __syncthreads();
  if (tid == 0) {
    int o = 0;
    for (int r = 0; r < 16; r++) { offs[r] = o; o += cnt[r]; }
    offs[16] = o;
    // greedy: largest bucket to least-loaded wave
    int load[NW];
    for (int w = 0; w < NW; w++) load[w] = 0;
    unsigned used = 0;
    for (int s = 0; s < 16; s++) {
      int best = 0, bc = -1;
      for (int r = 0; r < 16; r++)
        if (!((used >> r) & 1) && cnt[r] > bc) { bc = cnt[r]; best = r; }
      used |= 1u << best;
      int bw = 0;
      for (int w = 1; w < NW; w++) if (load[w] < load[bw]) bw = w;
      asg[best] = bw;
      load[bw] += bc;
    }
  }
  if (tid >= 128 && tid < 256) {
    int v = tid - 128;
    float d = fmaxf(degc[v], 1.0f);
    degc[v] = d;
    dinv[v] = 1.0f / d;
  }
  __syncthreads();
  if (tid < 16) cnt[tid] = offs[tid];  // cursors
  __syncthreads();
  for (int i = tid; i < EPG; i += NT) {
    int keep = useMask ? (int)((maskbits[i >> 5] >> (i & 31)) & 1u) : 1;
    if (keep) {
      int r = et_a[ge + i];
      int pos = atomicAdd(&cnt[r], 1);
      elist[pos] = ((unsigned)(src_a[ge + i] - gn) << 7) | (unsigned)(dst_a[ge + i] - gn);
    }
  }
  __syncthreads();
}

// ---------------------------------------------------------------------------
// RGCN layer (8 waves): lane = output column, W[:,lane] in 64 VGPRs.
//  phase 1: pre-seed hout[v] = (hin[v] @ Wself) * degc[v]   (16 nodes/wave)
//  phase 2: edges atomically add messages into hout (buckets over 8 waves)
//  phase 3: elementwise finalize hout = relu(hout * dinv + b)
// ---------------------------------------------------------------------------
__device__ void rgcn_layer(const float* hin, float* hout,
                           const float* degc, const float* dinv,
                           const unsigned* elist, const int* offs, const int* asg,
                           const float* __restrict__ Wl, const float* __restrict__ Wsl,
                           const float* __restrict__ bl, int tid) {
  int lane = tid & 63, wave = tid >> 6;
  // ---- phase 1: self pre-seed ----
  {
    float wc[64];
#pragma unroll
    for (int k = 0; k < 64; k++) wc[k] = Wsl[(k << 6) + lane];
    for (int v = (wave << 4); v < (wave << 4) + 16; v++) {
      float a0 = 0.f, a1 = 0.f, a2 = 0.f, a3 = 0.f;
      ROW_FMA(hin + (v << 6), wc, a0, a1, a2, a3);
      hout[(v << 6) + lane] = ((a0 + a1) + (a2 + a3)) * degc[v];
    }
  }
  __syncthreads();
  // ---- phase 2: edge pass ----
  for (int r = 0; r < 16; r++) {
    if (asg[r] != wave) continue;
    int base = offs[r], n = offs[r + 1] - base;
    if (n == 0) continue;
    const float* __restrict__ W = Wl + (r << 12);
    float wc[64];
#pragma unroll
    for (int k = 0; k < 64; k++) wc[k] = W[(k << 6) + lane];  // column, coalesced
    for (int c = 0; c < n; c += 64) {
      unsigned epack = elist[base + c + lane];  // 64 edges in the wave's lanes
      int m = (n - c < 64) ? (n - c) : 64;
      for (int i = 0; i < m; i++) {
        unsigned e = __builtin_amdgcn_readlane(epack, i);
        float a0 = 0.f, a1 = 0.f, a2 = 0.f, a3 = 0.f;
        ROW_FMA(hin + ((e >> 7) << 6), wc, a0, a1, a2, a3);
        atomicAdd(&hout[((e & 127) << 6) + lane], (a0 + a1) + (a2 + a3));
      }
    }
  }
  __syncthreads();
  // ---- phase 3: finalize ----
  for (int idx = tid; idx < 2048; idx += NT) {
    int v = idx >> 4;
    float4 a = ((float4*)hout)[idx];
    float4 bb = ((const float4*)bl)[idx & 15];
    float di = dinv[v];
    a.x = fmaxf(a.x * di + bb.x, 0.f);
    a.y = fmaxf(a.y * di + bb.y, 0.f);
    a.z = fmaxf(a.z * di + bb.z, 0.f);
    a.w = fmaxf(a.w * di + bb.w, 0.f);
    ((float4*)hout)[idx] = a;
  }
  __syncthreads();
}

// ---------------------------------------------------------------------------
// Dense 64x64, transposed (lane = column, W column in VGPRs, 16 nodes/wave).
// mode 0: out = acc ; 1: out = relu(acc+bias) ; 2: out += sqrt(exp(acc))*eps
// In-place (out==in) safe: each row fully read before written, per wave.
// ---------------------------------------------------------------------------
__device__ void dense64(const float* in, float* out, const float* __restrict__ W,
                        const float* __restrict__ bias, int mode,
                        const float* __restrict__ epsbuf, int gn, int tid) {
  int lane = tid & 63, wave = tid >> 6;
  float wc[64];
#pragma unroll
  for (int k = 0; k < 64; k++) wc[k] = W[(k << 6) + lane];
  float bj = (mode == 1) ? bias[lane] : 0.f;
  for (int v = (wave << 4); v < (wave << 4) + 16; v++) {
    float a0 = 0.f, a1 = 0.f, a2 = 0.f, a3 = 0.f;
    ROW_FMA(in + (v << 6), wc, a0, a1, a2, a3);
    float a = (a0 + a1) + (a2 + a3);
    if (mode == 1) a = fmaxf(a + bj, 0.f);
    else if (mode == 2)
      a = out[(v << 6) + lane] + sqrtf(expf(a)) * epsbuf[((gn + v) << 6) + lane];
    out[(v << 6) + lane] = a;
  }
  __syncthreads();
}

// ---------------------------------------------------------------------------
// Column-parallel pool over 8 waves: dst[j] = (1/128) * sum_v hout[v][j]
// ---------------------------------------------------------------------------
__device__ void pool64(const float* hout, float* red, float* dst, int tid) {
  int j = tid & 63, grp = tid >> 6;
  float s = 0.f;
  for (int v = (grp << 4); v < (grp << 4) + 16; v++) s += hout[(v << 6) + j];
  red[tid] = s;
  __syncthreads();
  if (tid < 64) {
    float t = 0.f;
#pragma unroll
    for (int w = 0; w < NW; w++) t += red[(w << 6) + tid];
    dst[tid] = t * (1.f / 128.f);
  }
  __syncthreads();
}

// ---------------------------------------------------------------------------
// Mega kernel: one workgroup (512 threads) per graph.
// ---------------------------------------------------------------------------
__global__ __launch_bounds__(NT, 4) void k_mega(
    const float* __restrict__ feat, const float* __restrict__ Wrel,
    const float* __restrict__ Wself, const float* __restrict__ bvec,
    const float* __restrict__ encWm, const float* __restrict__ encWs,
    const float* __restrict__ decWh, const float* __restrict__ dbh,
    const float* __restrict__ decWt, const float* __restrict__ dbt,
    const float* __restrict__ fcW, const float* __restrict__ fcb,
    const float* __restrict__ epsbuf,
    const int* __restrict__ srcA, const int* __restrict__ dstA, const int* __restrict__ etA,
    const int* __restrict__ asrcA, const int* __restrict__ adstA, const int* __restrict__ aetA,
    const int* __restrict__ rel_labels, float* __restrict__ ws, float* __restrict__ out) {
  __shared__ __align__(16) float buf0[NPG * 64];
  __shared__ __align__(16) float buf1[NPG * 64];
  __shared__ __align__(16) unsigned elist[EPG + 64];  // also reused to stage rel_e
  __shared__ float degc[NPG];
  __shared__ float dinv[NPG];
  __shared__ float red[NT];
  __shared__ float ht[384];
  __shared__ float rgout[192];
  __shared__ unsigned maskbits[EPG / 32];
  __shared__ int cnt[16];
  __shared__ int offs[17];
  __shared__ int asg[16];

  int g = blockIdx.x, tid = threadIdx.x;
  int gn = g * NPG, ge = g * EPG;
  float* repg = ws + WS_REPG;

  // ================= ORIG encode =================
  build_elist(elist, cnt, offs, asg, degc, dinv, maskbits, 0, etA, srcA, dstA, ge, gn, tid);
  for (int i = tid; i < 2048; i += NT)
    ((float4*)buf0)[i] = ((const float4*)(feat + gn * 64))[i];
  __syncthreads();
  for (int l = 0; l < 3; l++) {
    const float* hin = (l & 1) ? buf1 : buf0;
    float* hout = (l & 1) ? buf0 : buf1;
    rgcn_layer(hin, hout, degc, dinv, elist, offs, asg, Wrel + l * 65536,
               Wself + l * 4096, bvec + l * 64, tid);
    for (int i = tid; i < 2048; i += NT) {
      int v = i >> 4, q = i & 15;
      ((float4*)repg)[(gn + v) * 48 + l * 16 + q] = ((const float4*)hout)[i];
    }
    pool64(hout, red, out + OUT_G + g * 192 + l * 64, tid);
  }
  // ================= AUG encode =================
  build_elist(elist, cnt, offs, asg, degc, dinv, maskbits, 0, aetA, asrcA, adstA, ge, gn, tid);
  for (int i = tid; i < 2048; i += NT)
    ((float4*)buf0)[i] = ((const float4*)(feat + gn * 64))[i];
  __syncthreads();
  for (int l = 0; l < 3; l++) {
    const float* hin = (l & 1) ? buf1 : buf0;
    float* hout = (l & 1) ? buf0 : buf1;
    rgcn_layer(hin, hout, degc, dinv, elist, offs, asg, Wrel + l * 65536,
               Wself + l * 4096, bvec + l * 64, tid);
    pool64(hout, red, out + OUT_AUG + g * 192 + l * 64, tid);
  }
  // aug_x in buf1; reload x (= rep_g layer 2) into buf0 (coalesced).
  for (int i = tid; i < 2048; i += NT) {
    int v = i >> 4, q = i & 15;
    ((float4*)buf0)[i] = ((const float4*)repg)[(gn + v) * 48 + 32 + q];
  }
  __syncthreads();
  // ================= AdaIN (style into buf0); rotate-by-lane reads =================
  if (tid < NPG) {
    int v = tid;
    float s1 = 0.f, s2 = 0.f, t1 = 0.f, t2 = 0.f;
    for (int jj = 0; jj < 64; jj++) {
      int j = (v + jj) & 63;
      float x = buf0[(v << 6) + j];
      float y = buf1[(v << 6) + j];
      s1 += x; s2 += x * x; t1 += y; t2 += y * y;
    }
    float mc = s1 * (1.f / 64.f);
    float sc = sqrtf((s2 - 64.f * mc * mc) * (1.f / 63.f) + EPSV);
    float ms = t1 * (1.f / 64.f);
    float ss = sqrtf((t2 - 64.f * ms * ms) * (1.f / 63.f) + EPSV);
    float sca = ss / sc;
    for (int jj = 0; jj < 64; jj++) {
      int j = (v + jj) & 63;
      buf0[(v << 6) + j] = (buf0[(v << 6) + j] - mc) * sca + ms;
    }
  }
  __syncthreads();
  // ================= VAE + decoder node transforms =================
  dense64(buf0, buf1, encWm, nullptr, 0, nullptr, gn, tid);   // buf1 = z_mean
  dense64(buf0, buf1, encWs, nullptr, 2, epsbuf, gn, tid);    // buf1 = z
  dense64(buf1, buf0, decWh, dbh, 1, nullptr, gn, tid);       // buf0 = zh
  dense64(buf1, buf1, decWt, dbt, 1, nullptr, gn, tid);       // buf1 = zt (in-place safe)
  // ================= stage rel_e into dead elist space =================
  float* relEl = (float*)elist;
  for (int i = tid; i < 1024; i += NT) relEl[i] = ws[WS_RELE + i];
  for (int i = tid; i < EPG / 32; i += NT) maskbits[i] = 0u;
  __syncthreads();
  // ================= edge logits -> mask bits (rotate reads) =================
  for (int i = tid; i < EPG; i += NT) {
    int s = srcA[ge + i] - gn, t = dstA[ge + i] - gn, r = etA[ge + i];
    int rot = (s + t) & 63;
    float lg = 0.f;
    for (int jj = 0; jj < 64; jj++) {
      int j = (rot + jj) & 63;
      lg = fmaf(buf0[(s << 6) + j] * buf1[(t << 6) + j], relEl[(r << 6) + j], lg);
    }
    if (lg >= 0.5f) atomicOr(&maskbits[i >> 5], 1u << (i & 31));
  }
  __syncthreads();
  if (tid == 0) maskbits[0] |= 1u;  // root edge forced kept
  __syncthreads();
  // ================= RECON encode (masked edges skipped) =================
  build_elist(elist, cnt, offs, asg, degc, dinv, maskbits, 1, etA, srcA, dstA, ge, gn, tid);
  for (int i = tid; i < 2048; i += NT)
    ((float4*)buf0)[i] = ((const float4*)(feat + gn * 64))[i];
  __syncthreads();
  const float c1 = 1.0f / (65536.0f * 64.0f);  // mse: mean over N and D
  const float c2 = PHI / 65536.0f;             // style: PHI * mean over N
  for (int l = 0; l < 3; l++) {
    const float* hin = (l & 1) ? buf1 : buf0;
    float* hout = (l & 1) ? buf0 : buf1;
    float* gbuf = (l & 1) ? buf1 : buf0;  // hin buffer, dead after layer
    rgcn_layer(hin, hout, degc, dinv, elist, offs, asg, Wrel + l * 65536,
               Wself + l * 4096, bvec + l * 64, tid);
    // pool -> rgout[l]; head/tail rows -> ht
    {
      int j = tid & 63, grp = tid >> 6;
      float s = 0.f;
      for (int v = (grp << 4); v < (grp << 4) + 16; v++) s += hout[(v << 6) + j];
      red[tid] = s;
      __syncthreads();
      if (tid < 64) {
        float t = 0.f;
#pragma unroll
        for (int w = 0; w < NW; w++) t += red[(w << 6) + tid];
        rgout[l * 64 + tid] = t * (1.f / 128.f);
      }
      if (tid >= 64 && tid < 192) {
        int i2 = tid - 64;  // rows 0 (head) and 1 (tail)
        ht[(l * 2 + (i2 >> 6)) * 64 + (i2 & 63)] = hout[((i2 >> 6) << 6) + (i2 & 63)];
      }
      __syncthreads();
    }
    // reload rep_g layer l into gbuf (coalesced), then per-node loss stats
    for (int i = tid; i < 2048; i += NT) {
      int v = i >> 4, q = i & 15;
      ((float4*)gbuf)[i] = ((const float4*)repg)[(gn + v) * 48 + l * 16 + q];
    }
    __syncthreads();
    if (tid < NPG) {
      int v = tid;
      float mse = 0.f, a1 = 0.f, a2 = 0.f, b1 = 0.f, b2 = 0.f;
      for (int jj = 0; jj < 64; jj++) {
        int j = (v + jj) & 63;
        float rc = hout[(v << 6) + j];
        float gg = gbuf[(v << 6) + j];
        float d = rc - gg;
        mse += d * d; a1 += rc; a2 += rc * rc; b1 += gg; b2 += gg * gg;
      }
      float mr = a1 * (1.f / 64.f), mg = b1 * (1.f / 64.f);
      float sr = sqrtf((a2 - 64.f * mr * mr) * (1.f / 63.f) + EPSV);
      float sg = sqrtf((b2 - 64.f * mg * mg) * (1.f / 63.f) + EPSV);
      float style = (mr - mg) * (mr - mg) + (sr - sg) * (sr - sg);
      red[v] = mse * c1 + style * c2;
    }
    __syncthreads();
    if (tid < 64) {
      float x = red[tid] + red[tid + 64];
#pragma unroll
      for (int o = 32; o > 0; o >>= 1) x += __shfl_down(x, o);
      if (tid == 0) atomicAdd(&out[OUT_LOSS], x);
    }
    __syncthreads();
  }
  // ================= final fc output =================
  if (tid < 64) {
    int rl = rel_labels[g];
    const float* emb = ws + WS_EMB + rl * 64;
    float s = 0.f;
    for (int p = 0; p < 10; p++) {
      int i = p * 64 + tid;
      float gr;
      if (i < 192) gr = rgout[i];
      else if (i < 384) { int i2 = i - 192; gr = ht[((i2 >> 6) * 2 + 0) * 64 + (i2 & 63)]; }
      else if (i < 576) { int i2 = i - 384; gr = ht[((i2 >> 6) * 2 + 1) * 64 + (i2 & 63)]; }
      else gr = emb[i - 576];
      s = fmaf(gr, fcW[i], s);
    }
#pragma unroll
    for (int o = 32; o > 0; o >>= 1) s += __shfl_down(s, o);
    if (tid == 0) out[g] = s + fcb[0];
  }
}

extern "C" void kernel_launch(void* const* d_in, const int* in_sizes, int n_in,
                              void* d_out, int out_size, void* d_ws, size_t ws_size,
                              hipStream_t stream) {
  const float* feat     = (const float*)d_in[0];
  const float* rel_feat = (const float*)d_in[1];
  const float* rpW      = (const float*)d_in[2];
  const float* rpb      = (const float*)d_in[3];
  const float* Wrel     = (const float*)d_in[4];
  const float* Wself    = (const float*)d_in[5];
  const float* bvec     = (const float*)d_in[6];
  const float* encWm    = (const float*)d_in[7];
  const float* encWs    = (const float*)d_in[8];
  const float* decWh    = (const float*)d_in[9];
  const float* dbh      = (const float*)d_in[10];
  const float* decWt    = (const float*)d_in[11];
  const float* dbt      = (const float*)d_in[12];
  const float* decWr    = (const float*)d_in[13];
  const float* dbr      = (const float*)d_in[14];
  const float* fcW      = (const float*)d_in[15];
  const float* fcb      = (const float*)d_in[16];
  const float* epsb     = (const float*)d_in[17];
  const int* srcA  = (const int*)d_in[18];
  const int* dstA  = (const int*)d_in[19];
  const int* etA   = (const int*)d_in[20];
  const int* asrcA = (const int*)d_in[21];
  const int* adstA = (const int*)d_in[22];
  const int* aetA  = (const int*)d_in[23];
  const int* rel_labels = (const int*)d_in[25];
  float* out = (float*)d_out;
  float* ws  = (float*)d_ws;

  k_prologue<<<1, 256, 0, stream>>>(rel_feat, rpW, rpb, decWr, dbr, ws, out);
  k_mega<<<BG, NT, 0, stream>>>(feat, Wrel, Wself, bvec, encWm, encWs, decWh, dbh,
                                decWt, dbt, fcW, fcb, epsb, srcA, dstA, etA,
                                asrcA, adstA, aetA, rel_labels, ws, out);
}

// Round 5
// 2602.047 us; speedup vs baseline: 2.1789x; 1.0580x over previous
//
#include <hip/hip_runtime.h>
#include <hip/hip_bf16.h>

// Problem constants (fixed by the reference)
#define NPG    128       // nodes per graph
#define EPG    1024      // edges per graph
#define BG     512       // graphs
#define NT     512       // threads per block (8 waves)
#define NW     8         // waves per block
#define PHI    0.1f
#define EPSV   1e-5f

// d_out float offsets: output[512] | g_out[512*192] | aug_g_out[512*192] | loss[1]
#define OUT_G    512
#define OUT_AUG  98816
#define OUT_LOSS 197120

// workspace float offsets
#define WS_EMB  0          // emb_rel [16*64]
#define WS_RELE 1024       // rel_e   [16*64]
#define WS_REPG 2048       // rep_g   [65536*192]

// Uniform-row FMA, chunked: 4x ds_read_b128 then 16 FMAs, x4. Bounds live
// staging registers to ~16 so total wave pressure stays under 128 VGPRs.
#define ROW_FMA(hrptr, wcarr, a0, a1, a2, a3)                                  \
  {                                                                            \
    const float4* hr4_ = (const float4*)(hrptr);                               \
    _Pragma("unroll") for (int c_ = 0; c_ < 4; c_++) {                         \
      float4 h0_ = hr4_[4 * c_ + 0];                                           \
      float4 h1_ = hr4_[4 * c_ + 1];                                           \
      float4 h2_ = hr4_[4 * c_ + 2];                                           \
      float4 h3_ = hr4_[4 * c_ + 3];                                           \
      a0 = fmaf(h0_.x, wcarr[16 * c_ + 0], a0);                                \
      a1 = fmaf(h0_.y, wcarr[16 * c_ + 1], a1);                                \
      a2 = fmaf(h0_.z, wcarr[16 * c_ + 2], a2);                                \
      a3 = fmaf(h0_.w, wcarr[16 * c_ + 3], a3);                                \
      a0 = fmaf(h1_.x, wcarr[16 * c_ + 4], a0);                                \
      a1 = fmaf(h1_.y, wcarr[16 * c_ + 5], a1);                                \
      a2 = fmaf(h1_.z, wcarr[16 * c_ + 6], a2);                                \
      a3 = fmaf(h1_.w, wcarr[16 * c_ + 7], a3);                                \
      a0 = fmaf(h2_.x, wcarr[16 * c_ + 8], a0);                                \
      a1 = fmaf(h2_.y, wcarr[16 * c_ + 9], a1);                                \
      a2 = fmaf(h2_.z, wcarr[16 * c_ + 10], a2);                               \
      a3 = fmaf(h2_.w, wcarr[16 * c_ + 11], a3);                               \
      a0 = fmaf(h3_.x, wcarr[16 * c_ + 12], a0);                               \
      a1 = fmaf(h3_.y, wcarr[16 * c_ + 13], a1);                               \
      a2 = fmaf(h3_.z, wcarr[16 * c_ + 14], a2);                               \
      a3 = fmaf(h3_.w, wcarr[16 * c_ + 15], a3);                               \
    }                                                                          \
  }

// ---------------------------------------------------------------------------
// Prologue (transposed): emb_rel = relu(rel_feat @ rpW + rpb);
// rel_e = relu(emb_rel @ dWr + dbr). lane = output column, W column in VGPRs.
// ---------------------------------------------------------------------------
__global__ __launch_bounds__(256) void k_prologue(
    const float* __restrict__ rel_feat, const float* __restrict__ rpW,
    const float* __restrict__ rpb, const float* __restrict__ dWr,
    const float* __restrict__ dbr, float* __restrict__ ws, float* __restrict__ out) {
  __shared__ __align__(16) float emb[1024];
  int tid = threadIdx.x, lane = tid & 63, wave = tid >> 6;
  {
    float wc[64];
#pragma unroll
    for (int k = 0; k < 64; k++) wc[k] = rpW[(k << 6) + lane];
    float bj = rpb[lane];
    for (int r = (wave << 2); r < (wave << 2) + 4; r++) {
      float a0 = 0.f, a1 = 0.f, a2 = 0.f, a3 = 0.f;
      ROW_FMA(rel_feat + (r << 6), wc, a0, a1, a2, a3);
      float s = fmaxf((a0 + a1) + (a2 + a3) + bj, 0.f);
      emb[(r << 6) + lane] = s;
      ws[WS_EMB + (r << 6) + lane] = s;
    }
  }
  __syncthreads();
  {
    float wc[64];
#pragma unroll
    for (int k = 0; k < 64; k++) wc[k] = dWr[(k << 6) + lane];
    float bj = dbr[lane];
    for (int r = (wave << 2); r < (wave << 2) + 4; r++) {
      float a0 = 0.f, a1 = 0.f, a2 = 0.f, a3 = 0.f;
      ROW_FMA(emb + (r << 6), wc, a0, a1, a2, a3);
      ws[WS_RELE + (r << 6) + lane] = fmaxf((a0 + a1) + (a2 + a3) + bj, 0.f);
    }
  }
  if (tid == 0) out[OUT_LOSS] = 0.f;
}

// ---------------------------------------------------------------------------
// Build compact per-graph edge list bucketed by etype + clipped degree and
// its reciprocal + greedy wave assignment (balance bucket sizes over 8 waves).
// entry: (src 7b << 7) | dst 7b   (etype implicit from bucket)
// ---------------------------------------------------------------------------
__device__ void build_elist(unsigned* elist, int* cnt, int* offs, int* asg,
                            float* degc, float* dinv,
                            const unsigned* maskbits, int useMask,
                            const int* __restrict__ et_a, const int* __restrict__ src_a,
                            const int* __restrict__ dst_a, int ge, int gn, int tid) {
  if (tid < 16) cnt[tid] = 0;
  if (tid >= 128 && tid < 256) degc[tid - 128] = 0.f;
  __syncthreads();
  for (int i = tid; i < EPG; i += NT) {
    int keep = useMask ? (int)((maskbits[i >> 5] >> (i & 31)) & 1u) : 1;
    if (keep) {
      atomicAdd(&cnt[et_a[ge + i]], 1);
      atomicAdd(&degc[dst_a[ge + i] - gn], 1.f);
    }
  }
  __syncthreads();
  if (tid == 0) {
    int o = 0;
    for (int r = 0; r < 16; r++) { offs[r] = o; o += cnt[r]; }
    offs[16] = o;
    // greedy: largest bucket to least-loaded wave
    int load[NW];
    for (int w = 0; w < NW; w++) load[w] = 0;
    unsigned used = 0;
    for (int s = 0; s < 16; s++) {
      int best = 0, bc = -1;
      for (int r = 0; r < 16; r++)
        if (!((used >> r) & 1) && cnt[r] > bc) { bc = cnt[r]; best = r; }
      used |= 1u << best;
      int bw = 0;
      for (int w = 1; w < NW; w++) if (load[w] < load[bw]) bw = w;
      asg[best] = bw;
      load[bw] += bc;
    }
  }
  if (tid >= 128 && tid < 256) {
    int v = tid - 128;
    float d = fmaxf(degc[v], 1.0f);
    degc[v] = d;
    dinv[v] = 1.0f / d;
  }
  __syncthreads();
  if (tid < 16) cnt[tid] = offs[tid];  // cursors
  __syncthreads();
  for (int i = tid; i < EPG; i += NT) {
    int keep = useMask ? (int)((maskbits[i >> 5] >> (i & 31)) & 1u) : 1;
    if (keep) {
      int r = et_a[ge + i];
      int pos = atomicAdd(&cnt[r], 1);
      elist[pos] = ((unsigned)(src_a[ge + i] - gn) << 7) | (unsigned)(dst_a[ge + i] - gn);
    }
  }
  __syncthreads();
}

// ---------------------------------------------------------------------------
// RGCN layer (8 waves): lane = output column, W[:,lane] in 64 VGPRs.
//  phase 1: pre-seed hout[v] = (hin[v] @ Wself) * degc[v]   (16 nodes/wave)
//  phase 2: edges atomically add messages into hout (buckets over 8 waves)
//  phase 3: elementwise finalize hout = relu(hout * dinv + b)
// ---------------------------------------------------------------------------
__device__ void rgcn_layer(const float* hin, float* hout,
                           const float* degc, const float* dinv,
                           const unsigned* elist, const int* offs, const int* asg,
                           const float* __restrict__ Wl, const float* __restrict__ Wsl,
                           const float* __restrict__ bl, int tid) {
  int lane = tid & 63, wave = tid >> 6;
  // ---- phase 1: self pre-seed ----
  {
    float wc[64];
#pragma unroll
    for (int k = 0; k < 64; k++) wc[k] = Wsl[(k << 6) + lane];
    for (int v = (wave << 4); v < (wave << 4) + 16; v++) {
      float a0 = 0.f, a1 = 0.f, a2 = 0.f, a3 = 0.f;
      ROW_FMA(hin + (v << 6), wc, a0, a1, a2, a3);
      hout[(v << 6) + lane] = ((a0 + a1) + (a2 + a3)) * degc[v];
    }
  }
  __syncthreads();
  // ---- phase 2: edge pass ----
  for (int r = 0; r < 16; r++) {
    if (asg[r] != wave) continue;
    int base = offs[r], n = offs[r + 1] - base;
    if (n == 0) continue;
    const float* __restrict__ W = Wl + (r << 12);
    float wc[64];
#pragma unroll
    for (int k = 0; k < 64; k++) wc[k] = W[(k << 6) + lane];  // column, coalesced
    for (int c = 0; c < n; c += 64) {
      unsigned epack = elist[base + c + lane];  // 64 edges in the wave's lanes
      int m = (n - c < 64) ? (n - c) : 64;
      for (int i = 0; i < m; i++) {
        unsigned e = __builtin_amdgcn_readlane(epack, i);
        float a0 = 0.f, a1 = 0.f, a2 = 0.f, a3 = 0.f;
        ROW_FMA(hin + ((e >> 7) << 6), wc, a0, a1, a2, a3);
        atomicAdd(&hout[((e & 127) << 6) + lane], (a0 + a1) + (a2 + a3));
      }
    }
  }
  __syncthreads();
  // ---- phase 3: finalize ----
  for (int idx = tid; idx < 2048; idx += NT) {
    int v = idx >> 4;
    float4 a = ((float4*)hout)[idx];
    float4 bb = ((const float4*)bl)[idx & 15];
    float di = dinv[v];
    a.x = fmaxf(a.x * di + bb.x, 0.f);
    a.y = fmaxf(a.y * di + bb.y, 0.f);
    a.z = fmaxf(a.z * di + bb.z, 0.f);
    a.w = fmaxf(a.w * di + bb.w, 0.f);
    ((float4*)hout)[idx] = a;
  }
  __syncthreads();
}

// ---------------------------------------------------------------------------
// Dense 64x64, transposed (lane = column, W column in VGPRs, 16 nodes/wave).
// mode 0: out = acc ; 1: out = relu(acc+bias) ; 2: out += sqrt(exp(acc))*eps
// In-place (out==in) safe: each row fully read before written, per wave.
// ---------------------------------------------------------------------------
__device__ void dense64(const float* in, float* out, const float* __restrict__ W,
                        const float* __restrict__ bias, int mode,
                        const float* __restrict__ epsbuf, int gn, int tid) {
  int lane = tid & 63, wave = tid >> 6;
  float wc[64];
#pragma unroll
  for (int k = 0; k < 64; k++) wc[k] = W[(k << 6) + lane];
  float bj = (mode == 1) ? bias[lane] : 0.f;
  for (int v = (wave << 4); v < (wave << 4) + 16; v++) {
    float a0 = 0.f, a1 = 0.f, a2 = 0.f, a3 = 0.f;
    ROW_FMA(in + (v << 6), wc, a0, a1, a2, a3);
    float a = (a0 + a1) + (a2 + a3);
    if (mode == 1) a = fmaxf(a + bj, 0.f);
    else if (mode == 2)
      a = out[(v << 6) + lane] + sqrtf(expf(a)) * epsbuf[((gn + v) << 6) + lane];
    out[(v << 6) + lane] = a;
  }
  __syncthreads();
}

// ---------------------------------------------------------------------------
// Column-parallel pool over 8 waves: dst[j] = (1/128) * sum_v hout[v][j]
// ---------------------------------------------------------------------------
__device__ void pool64(const float* hout, float* red, float* dst, int tid) {
  int j = tid & 63, grp = tid >> 6;
  float s = 0.f;
  for (int v = (grp << 4); v < (grp << 4) + 16; v++) s += hout[(v << 6) + j];
  red[tid] = s;
  __syncthreads();
  if (tid < 64) {
    float t = 0.f;
#pragma unroll
    for (int w = 0; w < NW; w++) t += red[(w << 6) + tid];
    dst[tid] = t * (1.f / 128.f);
  }
  __syncthreads();
}

// ---------------------------------------------------------------------------
// Mega kernel: one workgroup (512 threads) per graph.
// launch_bounds minwaves=2 -> VGPR cap 256: room for wc[64] + staging, NO SPILL.
// Occupancy stays LDS-bound at 2 blocks/CU (75.8 KB each) = 16 waves/CU.
// ---------------------------------------------------------------------------
__global__ __launch_bounds__(NT, 2) void k_mega(
    const float* __restrict__ feat, const float* __restrict__ Wrel,
    const float* __restrict__ Wself, const float* __restrict__ bvec,
    const float* __restrict__ encWm, const float* __restrict__ encWs,
    const float* __restrict__ decWh, const float* __restrict__ dbh,
    const float* __restrict__ decWt, const float* __restrict__ dbt,
    const float* __restrict__ fcW, const float* __restrict__ fcb,
    const float* __restrict__ epsbuf,
    const int* __restrict__ srcA, const int* __restrict__ dstA, const int* __restrict__ etA,
    const int* __restrict__ asrcA, const int* __restrict__ adstA, const int* __restrict__ aetA,
    const int* __restrict__ rel_labels, float* __restrict__ ws, float* __restrict__ out) {
  __shared__ __align__(16) float buf0[NPG * 64];
  __shared__ __align__(16) float buf1[NPG * 64];
  __shared__ __align__(16) unsigned elist[EPG + 64];  // also reused to stage rel_e
  __shared__ float degc[NPG];
  __shared__ float dinv[NPG];
  __shared__ float red[NT];
  __shared__ float ht[384];
  __shared__ float rgout[192];
  __shared__ unsigned maskbits[EPG / 32];
  __shared__ int cnt[16];
  __shared__ int offs[17];
  __shared__ int asg[16];

  int g = blockIdx.x, tid = threadIdx.x;
  int gn = g * NPG, ge = g * EPG;
  float* repg = ws + WS_REPG;

  // ================= ORIG encode =================
  build_elist(elist, cnt, offs, asg, degc, dinv, maskbits, 0, etA, srcA, dstA, ge, gn, tid);
  for (int i = tid; i < 2048; i += NT)
    ((float4*)buf0)[i] = ((const float4*)(feat + gn * 64))[i];
  __syncthreads();
  for (int l = 0; l < 3; l++) {
    const float* hin = (l & 1) ? buf1 : buf0;
    float* hout = (l & 1) ? buf0 : buf1;
    rgcn_layer(hin, hout, degc, dinv, elist, offs, asg, Wrel + l * 65536,
               Wself + l * 4096, bvec + l * 64, tid);
    for (int i = tid; i < 2048; i += NT) {
      int v = i >> 4, q = i & 15;
      ((float4*)repg)[(gn + v) * 48 + l * 16 + q] = ((const float4*)hout)[i];
    }
    pool64(hout, red, out + OUT_G + g * 192 + l * 64, tid);
  }
  // ================= AUG encode =================
  build_elist(elist, cnt, offs, asg, degc, dinv, maskbits, 0, aetA, asrcA, adstA, ge, gn, tid);
  for (int i = tid; i < 2048; i += NT)
    ((float4*)buf0)[i] = ((const float4*)(feat + gn * 64))[i];
  __syncthreads();
  for (int l = 0; l < 3; l++) {
    const float* hin = (l & 1) ? buf1 : buf0;
    float* hout = (l & 1) ? buf0 : buf1;
    rgcn_layer(hin, hout, degc, dinv, elist, offs, asg, Wrel + l * 65536,
               Wself + l * 4096, bvec + l * 64, tid);
    pool64(hout, red, out + OUT_AUG + g * 192 + l * 64, tid);
  }
  // aug_x in buf1; reload x (= rep_g layer 2) into buf0 (coalesced).
  for (int i = tid; i < 2048; i += NT) {
    int v = i >> 4, q = i & 15;
    ((float4*)buf0)[i] = ((const float4*)repg)[(gn + v) * 48 + 32 + q];
  }
  __syncthreads();
  // ================= AdaIN (style into buf0); rotate-by-lane reads =================
  if (tid < NPG) {
    int v = tid;
    float s1 = 0.f, s2 = 0.f, t1 = 0.f, t2 = 0.f;
    for (int jj = 0; jj < 64; jj++) {
      int j = (v + jj) & 63;
      float x = buf0[(v << 6) + j];
      float y = buf1[(v << 6) + j];
      s1 += x; s2 += x * x; t1 += y; t2 += y * y;
    }
    float mc = s1 * (1.f / 64.f);
    float sc = sqrtf((s2 - 64.f * mc * mc) * (1.f / 63.f) + EPSV);
    float ms = t1 * (1.f / 64.f);
    float ss = sqrtf((t2 - 64.f * ms * ms) * (1.f / 63.f) + EPSV);
    float sca = ss / sc;
    for (int jj = 0; jj < 64; jj++) {
      int j = (v + jj) & 63;
      buf0[(v << 6) + j] = (buf0[(v << 6) + j] - mc) * sca + ms;
    }
  }
  __syncthreads();
  // ================= VAE + decoder node transforms =================
  dense64(buf0, buf1, encWm, nullptr, 0, nullptr, gn, tid);   // buf1 = z_mean
  dense64(buf0, buf1, encWs, nullptr, 2, epsbuf, gn, tid);    // buf1 = z
  dense64(buf1, buf0, decWh, dbh, 1, nullptr, gn, tid);       // buf0 = zh
  dense64(buf1, buf1, decWt, dbt, 1, nullptr, gn, tid);       // buf1 = zt (in-place safe)
  // ================= stage rel_e into dead elist space =================
  float* relEl = (float*)elist;
  for (int i = tid; i < 1024; i += NT) relEl[i] = ws[WS_RELE + i];
  for (int i = tid; i < EPG / 32; i += NT) maskbits[i] = 0u;
  __syncthreads();
  // ================= edge logits -> mask bits (rotate reads) =================
  for (int i = tid; i < EPG; i += NT) {
    int s = srcA[ge + i] - gn, t = dstA[ge + i] - gn, r = etA[ge + i];
    int rot = (s + t) & 63;
    float lg = 0.f;
    for (int jj = 0; jj < 64; jj++) {
      int j = (rot + jj) & 63;
      lg = fmaf(buf0[(s << 6) + j] * buf1[(t << 6) + j], relEl[(r << 6) + j], lg);
    }
    if (lg >= 0.5f) atomicOr(&maskbits[i >> 5], 1u << (i & 31));
  }
  __syncthreads();
  if (tid == 0) maskbits[0] |= 1u;  // root edge forced kept
  __syncthreads();
  // ================= RECON encode (masked edges skipped) =================
  build_elist(elist, cnt, offs, asg, degc, dinv, maskbits, 1, etA, srcA, dstA, ge, gn, tid);
  for (int i = tid; i < 2048; i += NT)
    ((float4*)buf0)[i] = ((const float4*)(feat + gn * 64))[i];
  __syncthreads();
  const float c1 = 1.0f / (65536.0f * 64.0f);  // mse: mean over N and D
  const float c2 = PHI / 65536.0f;             // style: PHI * mean over N
  for (int l = 0; l < 3; l++) {
    const float* hin = (l & 1) ? buf1 : buf0;
    float* hout = (l & 1) ? buf0 : buf1;
    float* gbuf = (l & 1) ? buf1 : buf0;  // hin buffer, dead after layer
    rgcn_layer(hin, hout, degc, dinv, elist, offs, asg, Wrel + l * 65536,
               Wself + l * 4096, bvec + l * 64, tid);
    // pool -> rgout[l]; head/tail rows -> ht
    {
      int j = tid & 63, grp = tid >> 6;
      float s = 0.f;
      for (int v = (grp << 4); v < (grp << 4) + 16; v++) s += hout[(v << 6) + j];
      red[tid] = s;
      __syncthreads();
      if (tid < 64) {
        float t = 0.f;
#pragma unroll
        for (int w = 0; w < NW; w++) t += red[(w << 6) + tid];
        rgout[l * 64 + tid] = t * (1.f / 128.f);
      }
      if (tid >= 64 && tid < 192) {
        int i2 = tid - 64;  // rows 0 (head) and 1 (tail)
        ht[(l * 2 + (i2 >> 6)) * 64 + (i2 & 63)] = hout[((i2 >> 6) << 6) + (i2 & 63)];
      }
      __syncthreads();
    }
    // reload rep_g layer l into gbuf (coalesced), then per-node loss stats
    for (int i = tid; i < 2048; i += NT) {
      int v = i >> 4, q = i & 15;
      ((float4*)gbuf)[i] = ((const float4*)repg)[(gn + v) * 48 + l * 16 + q];
    }
    __syncthreads();
    if (tid < NPG) {
      int v = tid;
      float mse = 0.f, a1 = 0.f, a2 = 0.f, b1 = 0.f, b2 = 0.f;
      for (int jj = 0; jj < 64; jj++) {
        int j = (v + jj) & 63;
        float rc = hout[(v << 6) + j];
        float gg = gbuf[(v << 6) + j];
        float d = rc - gg;
        mse += d * d; a1 += rc; a2 += rc * rc; b1 += gg; b2 += gg * gg;
      }
      float mr = a1 * (1.f / 64.f), mg = b1 * (1.f / 64.f);
      float sr = sqrtf((a2 - 64.f * mr * mr) * (1.f / 63.f) + EPSV);
      float sg = sqrtf((b2 - 64.f * mg * mg) * (1.f / 63.f) + EPSV);
      float style = (mr - mg) * (mr - mg) + (sr - sg) * (sr - sg);
      red[v] = mse * c1 + style * c2;
    }
    __syncthreads();
    if (tid < 64) {
      float x = red[tid] + red[tid + 64];
#pragma unroll
      for (int o = 32; o > 0; o >>= 1) x += __shfl_down(x, o);
      if (tid == 0) atomicAdd(&out[OUT_LOSS], x);
    }
    __syncthreads();
  }
  // ================= final fc output =================
  if (tid < 64) {
    int rl = rel_labels[g];
    const float* emb = ws + WS_EMB + rl * 64;
    float s = 0.f;
    for (int p = 0; p < 10; p++) {
      int i = p * 64 + tid;
      float gr;
      if (i < 192) gr = rgout[i];
      else if (i < 384) { int i2 = i - 192; gr = ht[((i2 >> 6) * 2 + 0) * 64 + (i2 & 63)]; }
      else if (i < 576) { int i2 = i - 384; gr = ht[((i2 >> 6) * 2 + 1) * 64 + (i2 & 63)]; }
      else gr = emb[i - 576];
      s = fmaf(gr, fcW[i], s);
    }
#pragma unroll
    for (int o = 32; o > 0; o >>= 1) s += __shfl_down(s, o);
    if (tid == 0) out[g] = s + fcb[0];
  }
}

extern "C" void kernel_launch(void* const* d_in, const int* in_sizes, int n_in,
                              void* d_out, int out_size, void* d_ws, size_t ws_size,
                              hipStream_t stream) {
  const float* feat     = (const float*)d_in[0];
  const float* rel_feat = (const float*)d_in[1];
  const float* rpW      = (const float*)d_in[2];
  const float* rpb      = (const float*)d_in[3];
  const float* Wrel     = (const float*)d_in[4];
  const float* Wself    = (const float*)d_in[5];
  const float* bvec     = (const float*)d_in[6];
  const float* encWm    = (const float*)d_in[7];
  const float* encWs    = (const float*)d_in[8];
  const float* decWh    = (const float*)d_in[9];
  const float* dbh      = (const float*)d_in[10];
  const float* decWt    = (const float*)d_in[11];
  const float* dbt      = (const float*)d_in[12];
  const float* decWr    = (const float*)d_in[13];
  const float* dbr      = (const float*)d_in[14];
  const float* fcW      = (const float*)d_in[15];
  const float* fcb      = (const float*)d_in[16];
  const float* epsb     = (const float*)d_in[17];
  const int* srcA  = (const int*)d_in[18];
  const int* dstA  = (const int*)d_in[19];
  const int* etA   = (const int*)d_in[20];
  const int* asrcA = (const int*)d_in[21];
  const int* adstA = (const int*)d_in[22];
  const int* aetA  = (const int*)d_in[23];
  const int* rel_labels = (const int*)d_in[25];
  float* out = (float*)d_out;
  float* ws  = (float*)d_ws;

  k_prologue<<<1, 256, 0, stream>>>(rel_feat, rpW, rpb, decWr, dbr, ws, out);
  k_mega<<<BG, NT, 0, stream>>>(feat, Wrel, Wself, bvec, encWm, encWs, decWh, dbh,
                                decWt, dbt, fcW, fcb, epsb, srcA, dstA, etA,
                                asrcA, adstA, aetA, rel_labels, ws, out);
}